// Round 11
// baseline (405.833 us; speedup 1.0000x reference)
//
#include <hip/hip_runtime.h>

typedef __bf16 bf16_t;
typedef __bf16 bf16x8 __attribute__((ext_vector_type(8)));
typedef __bf16 bf16x4_v __attribute__((ext_vector_type(4)));
typedef float f32x4 __attribute__((ext_vector_type(4)));

#define AS1 __attribute__((address_space(1)))
#define AS3 __attribute__((address_space(3)))

__device__ __forceinline__ void gload_lds16(const void* g, void* l) {
    __builtin_amdgcn_global_load_lds((AS1 void*)(void*)g, (AS3 void*)l, 16, 0, 0);
}

// ---------------- routing: salpha[m][l][e] = zeta_agg[m][l] * alpha_agg[m][l][e]
__global__ void routing_kernel(
    const float* __restrict__ dom_emb, const float* __restrict__ layer_pos,
    const float* __restrict__ Wi1, const float* __restrict__ bi1,
    const float* __restrict__ Wi2, const float* __restrict__ bi2,
    const float* __restrict__ Wa1, const float* __restrict__ ba1,
    const float* __restrict__ Wa2, const float* __restrict__ ba2,
    const float* __restrict__ gate_logits, const float* __restrict__ R_benefit,
    float* __restrict__ salpha)
{
    constexpr int M = 8, L = 3, E = 4, H = 64;
    __shared__ float zl[M * L];
    __shared__ float al[M * L][E];
    __shared__ float zeta_all[M][L];
    __shared__ float alpha_all[M][L][E];
    const int t = threadIdx.x;
    const int ml = t >> 3, js = t & 7;
    if (ml < M * L) {
        const int m = ml / L, l = ml % L;
        float zacc = 0.f;
        float aacc[E] = {0.f, 0.f, 0.f, 0.f};
        for (int jj = 0; jj < 8; ++jj) {
            const int j = js * 8 + jj;
            float hz = bi1[j], ha = ba1[j];
            for (int i = 0; i < H; ++i) {
                const float de = dom_emb[m * H + i];
                const float lp = layer_pos[l * H + i];
                hz += de * Wi1[j * 2 * H + i] + lp * Wi1[j * 2 * H + H + i];
                ha += de * Wa1[j * 2 * H + i] + lp * Wa1[j * 2 * H + H + i];
            }
            hz = fmaxf(hz, 0.f); ha = fmaxf(ha, 0.f);
            zacc += hz * Wi2[j];
            for (int e = 0; e < E; ++e) aacc[e] += ha * Wa2[e * H + j];
        }
        #pragma unroll
        for (int off = 4; off >= 1; off >>= 1) {
            zacc += __shfl_down(zacc, off, 8);
            for (int e = 0; e < E; ++e) aacc[e] += __shfl_down(aacc[e], off, 8);
        }
        if (js == 0) {
            zl[ml] = zacc + bi2[0];
            for (int e = 0; e < E; ++e) al[ml][e] = aacc[e] + ba2[e];
        }
    }
    __syncthreads();
    if (t < M) {
        const int m = t;
        float v[3] = { zl[m * L + 0], zl[m * L + 1], zl[m * L + 2] };
        int di = 0; float dv = v[0];
        for (int i = 1; i < 3; ++i) if (v[i] <= dv) { dv = v[i]; di = i; }
        float mx = -1e30f;
        for (int i = 0; i < 3; ++i) if (i != di) mx = fmaxf(mx, v[i]);
        float s = 0.f, ev[3];
        for (int i = 0; i < 3; ++i) { ev[i] = (i == di) ? 0.f : expf(v[i] - mx); s += ev[i]; }
        for (int i = 0; i < 3; ++i) zeta_all[m][i] = ev[i] / s;
        for (int l = 0; l < L; ++l) {
            float a[4];
            for (int e = 0; e < 4; ++e) a[e] = al[m * L + l][e];
            int i1 = 0;
            for (int e = 1; e < 4; ++e) if (a[e] > a[i1]) i1 = e;
            int i2 = -1;
            for (int e = 0; e < 4; ++e) { if (e == i1) continue; if (i2 < 0 || a[e] > a[i2]) i2 = e; }
            const float mx2 = fmaxf(a[i1], a[i2]);
            const float e1 = expf(a[i1] - mx2), e2 = expf(a[i2] - mx2);
            const float ss = e1 + e2;
            for (int e = 0; e < 4; ++e) alpha_all[m][l][e] = 0.f;
            alpha_all[m][l][i1] = e1 / ss;
            alpha_all[m][l][i2] = e2 / ss;
        }
    }
    __syncthreads();
    if (t < M) {
        const int m = t;
        float Rrow[8]; float rs = 0.f;
        for (int n = 0; n < M; ++n) {
            const float g = gate_logits[m * M + n];
            const float rr = log1pf(expf(g)) * R_benefit[m * M + n];
            Rrow[n] = rr; rs += rr;
        }
        rs = fmaxf(rs, 1e-12f);
        for (int l = 0; l < L; ++l) {
            float zag = 0.f, aag[4] = {0.f, 0.f, 0.f, 0.f};
            for (int n = 0; n < M; ++n) {
                const float w = Rrow[n] / rs;
                zag += w * zeta_all[n][l];
                for (int e = 0; e < 4; ++e) aag[e] += w * alpha_all[n][l][e];
            }
            for (int e = 0; e < 4; ++e) salpha[(m * L + l) * 4 + e] = zag * aag[e];
        }
    }
}

// ---------------- fused f32->bf16 convert: W1,W2,W3,A1,A2,A3 into contiguous dst
__global__ void cvt_fused(const float* __restrict__ s0, const float* __restrict__ s1,
                          const float* __restrict__ s2, const float* __restrict__ s3,
                          const float* __restrict__ s4, const float* __restrict__ s5,
                          bf16_t* __restrict__ dst)
{
    const int i = blockIdx.x * 256 + threadIdx.x;   // float4 index
    constexpr int b0 = 1048576;
    constexpr int b1 = b0 + 524288;
    constexpr int b2 = b1 + 131072;
    constexpr int b3 = b2 + 16384;
    constexpr int b4 = b3 + 16384;
    constexpr int b5 = b4 + 8192;
    if (i >= b5) return;
    const float* src; int rel;
    if (i < b0)      { src = s0; rel = i; }
    else if (i < b1) { src = s1; rel = i - b0; }
    else if (i < b2) { src = s2; rel = i - b1; }
    else if (i < b3) { src = s3; rel = i - b2; }
    else if (i < b4) { src = s4; rel = i - b3; }
    else             { src = s5; rel = i - b4; }
    const float4 v = ((const float4*)src)[rel];
    bf16x4_v o;
    o[0] = (__bf16)v.x; o[1] = (__bf16)v.y; o[2] = (__bf16)v.z; o[3] = (__bf16)v.w;
    ((bf16x4_v*)dst)[i] = o;
}

// ---------------- fused Bepi pack: B [E][Dout][r] f32 -> [Dout][32] bf16, c=e*8+r
__global__ void bepi_fused(const float* __restrict__ B1, const float* __restrict__ B2,
                           const float* __restrict__ B3, bf16_t* __restrict__ dst)
{
    const int idx = blockIdx.x * 256 + threadIdx.x;
    constexpr int c1 = 2048 * 32, c2 = c1 + 1024 * 32, c3 = c2 + 512 * 32;
    if (idx >= c3) return;
    const float* B; int rel, Dout;
    if (idx < c1)      { B = B1; rel = idx;      Dout = 2048; }
    else if (idx < c2) { B = B2; rel = idx - c1; Dout = 1024; }
    else               { B = B3; rel = idx - c2; Dout = 512; }
    const int o = rel >> 5, c = rel & 31, e = c >> 3, r = c & 7;
    dst[idx] = (__bf16)B[((size_t)e * Dout + o) * 8 + r];
}

// ---------------- TW[b][c] = (sum_k h[b][k]*Acat[c][k]) * salpha[dom[b]][layer][c>>3]
template<bool F32IN>
__global__ void __launch_bounds__(256) tw_kernel(
    const void* __restrict__ hin, bf16_t* __restrict__ xb_out,
    const bf16_t* __restrict__ Acat, const float* __restrict__ salpha,
    const int* __restrict__ dom, const int layer, const int K,
    bf16_t* __restrict__ TWb)
{
    const int t = threadIdx.x, wid = t >> 6, lane = t & 63;
    const int rb = blockIdx.x * 64 + wid * 16;
    const int ln15 = lane & 15, kg = (lane >> 4) * 8;
    const int row = rb + ln15;
    f32x4 acc0 = {0.f, 0.f, 0.f, 0.f}, acc1 = {0.f, 0.f, 0.f, 0.f};
    const bf16_t* pa0 = Acat + (size_t)ln15 * K + kg;
    const bf16_t* pa1 = pa0 + (size_t)16 * K;
    for (int k0 = 0; k0 < K; k0 += 32) {
        bf16x8 a;
        if constexpr (F32IN) {
            const float* px = (const float*)hin + (size_t)row * K + k0 + kg;
            const float4 x0 = *(const float4*)px;
            const float4 x1 = *(const float4*)(px + 4);
            a[0] = (__bf16)x0.x; a[1] = (__bf16)x0.y; a[2] = (__bf16)x0.z; a[3] = (__bf16)x0.w;
            a[4] = (__bf16)x1.x; a[5] = (__bf16)x1.y; a[6] = (__bf16)x1.z; a[7] = (__bf16)x1.w;
            *(bf16x8*)(xb_out + (size_t)row * K + k0 + kg) = a;
        } else {
            a = *(const bf16x8*)((const bf16_t*)hin + (size_t)row * K + k0 + kg);
        }
        const bf16x8 b0 = *(const bf16x8*)(pa0 + k0);
        const bf16x8 b1 = *(const bf16x8*)(pa1 + k0);
        acc0 = __builtin_amdgcn_mfma_f32_16x16x32_bf16(a, b0, acc0, 0, 0, 0);
        acc1 = __builtin_amdgcn_mfma_f32_16x16x32_bf16(a, b1, acc1, 0, 0, 0);
    }
    const int rbase = rb + (lane >> 4) * 4;
    #pragma unroll
    for (int i = 0; i < 4; ++i) {
        const int r2 = rbase + i;
        const int d = dom[r2];
        const float* sa = salpha + (d * 3 + layer) * 4;
        const float s0 = sa[ln15 >> 3];
        const float s1 = sa[2 + (ln15 >> 3)];
        TWb[(size_t)r2 * 32 + ln15]      = (__bf16)(acc0[i] * s0);
        TWb[(size_t)r2 * 32 + 16 + ln15] = (__bf16)(acc1[i] * s1);
    }
}

// ================= 256x256 8-phase GEMM + fused LoRA K-step =================
// LDS chunk = 16KB = [kh:2][row:128][32 k] bf16, 64B rows; swizzle: 16B-slot
// bit1 ^= row bit3 (R5-verified conflict-free, SQ_LDS_BANK_CONFLICT=0).
// R11: addressing canonicalization (addresses IDENTICAL to R10, re-derived):
// all LDS reads as {aBase,bBase} + literal (ds_read offset: immediates, <64KB);
// stage sources as 4 persistent pointers + literal 64/128/192B offsets (13-bit
// global imm), advanced +256B per 2-tile unroll. Targets measured VALUBusy
// 17.6% (~930 cyc/K-tile of per-phase address recomputation on the critical
// path). Schedule/ledger/swizzle unchanged (plane staging P1:A.k0 P2:B.k0
// P3:A.k1 P4:B.k1 for T+1; vmcnt(4) at P2/P4; drain at last tile's P2).

__device__ __forceinline__ void stage_chunk32(const bf16_t* g, char* chunk, int t) {
    const int row = t >> 2;
    const int sl = t & 3;
    const int src = sl ^ (((row >> 3) & 1) << 1);
    gload_lds16(g + (size_t)row * 32 + src * 8, chunk + t * 16);
}

template<int K>
__global__ void __launch_bounds__(512, 2) gemm_lora8(
    const bf16_t* __restrict__ Abuf, const bf16_t* __restrict__ Wbuf,
    const float* __restrict__ bias, const bf16_t* __restrict__ TWb,
    const bf16_t* __restrict__ Bepi, bf16_t* __restrict__ outp,
    const int N, const int nwg_n)
{
    __shared__ __align__(1024) char lds[131072];
    const int t = threadIdx.x;
    const int wid = t >> 6, lane = t & 63;
    const int wm = wid >> 2, wn = wid & 3, wnh = wn >> 1;
    const int cpx = gridDim.x >> 3;
    const int wg = (blockIdx.x & 7) * cpx + (blockIdx.x >> 3);
    const int row0 = (wg / nwg_n) * 256, col0 = (wg % nwg_n) * 256;

    const int r15 = lane & 15;
    const int swb = ((lane >> 4) ^ (((lane >> 3) & 1) << 1)) << 4;

    // --- canonical per-wave LDS read bases (everything else is a literal) ---
    // A addr = aBase + p*32768 + kq*8192 + (mbase+i)*1024       (max 48128)
    // B addr = bBase + p*32768 + kq*8192 + nf*1024              (max 44032)
    const char* aBase = lds + (wm << 14) + (r15 << 6) + swb;
    const char* bBase = lds + 65536 + (wnh << 14) + ((wn & 1) << 12) + (r15 << 6) + swb;
    // stage dest base: plane = dBase + [65536 if B] + q*32768 + {0,8192,16384,24576}
    char* const dBase = lds + t * 16;

    // staging source ptrs (inverse-swizzled slot), literal offsets per pair
    const int srow = t >> 2, ssl = t & 3;
    const int ssrc = ssl ^ (((srow >> 3) & 1) << 1);
    const bf16_t* sA = Abuf + (size_t)(row0 + srow) * K + ssrc * 8;
    const bf16_t* sB = Wbuf + (size_t)(col0 + srow) * K + ssrc * 8;
    constexpr size_t halfA = (size_t)128 * K;

    f32x4 acc[8][4] = {};
    bf16x8 aF[4], bF[4];

    #define RD_A(P, KQ, MB) do { _Pragma("unroll") for (int i_ = 0; i_ < 4; ++i_) \
        aF[i_] = *(const bf16x8*)(aBase + (P)*32768 + (KQ)*8192 + ((MB)+i_)*1024); } while (0)
    #define RD_B(P, KQ) do { _Pragma("unroll") for (int n_ = 0; n_ < 4; ++n_) \
        bF[n_] = *(const bf16x8*)(bBase + (P)*32768 + (KQ)*8192 + n_*1024); } while (0)

    auto mfma16 = [&](int mbase) {
        __builtin_amdgcn_s_setprio(1);
        #pragma unroll
        for (int mf = 0; mf < 4; ++mf)
            #pragma unroll
            for (int nf = 0; nf < 4; ++nf)
                acc[mbase + mf][nf] =
                    __builtin_amdgcn_mfma_f32_16x16x32_bf16(aF[mf], bF[nf], acc[mbase + mf][nf], 0, 0, 0);
        __builtin_amdgcn_s_setprio(0);
    };
    #define BAR() __builtin_amdgcn_s_barrier()

    constexpr int NT = K >> 6;   // even, >= 16

    // Prologue: T0 planes in chain order {A.k0, B.k0, A.k1, B.k1} (parity 0)
    gload_lds16(sA,              dBase + 0);
    gload_lds16(sA + halfA,      dBase + 16384);
    gload_lds16(sB,              dBase + 65536);
    gload_lds16(sB + halfA,      dBase + 65536 + 16384);
    gload_lds16(sA + 32,         dBase + 8192);
    gload_lds16(sA + halfA + 32, dBase + 24576);
    gload_lds16(sB + 32,         dBase + 65536 + 8192);
    gload_lds16(sB + halfA + 32, dBase + 65536 + 24576);
    asm volatile("s_waitcnt vmcnt(4)" ::: "memory");
    __builtin_amdgcn_s_barrier();

    // stage sources for tile T+1 (advance +128 elems per 2-tile pair)
    const bf16_t* pA0 = sA + 64;
    const bf16_t* pA1 = sA + halfA + 64;
    const bf16_t* pB0 = sB + 64;
    const bf16_t* pB1 = sB + halfA + 64;

    // One K-tile: parity P (literal), MORE (literal), TOFF = staged-tile offset
    // (0 for TILE slot 0, 64 for slot 1). Q = P^1 = staging parity.
    #define TILE(P, MORE, TOFF) do {                                            \
        /* P1: (mf0-3, kq0); stage T+1.A.k0 */                                   \
        RD_A(P, 0, 0);                                                           \
        RD_B(P, 0);                                                              \
        if (MORE) { gload_lds16(pA0 + (TOFF), dBase + ((P)^1)*32768 + 0);        \
                    gload_lds16(pA1 + (TOFF), dBase + ((P)^1)*32768 + 16384); }  \
        BAR();                                                                   \
        mfma16(0);                                                               \
        BAR();                                                                   \
        /* P2: (mf4-7, kq0); stage T+1.B.k0; wait covers T.k1 planes */          \
        RD_A(P, 0, 4);                                                           \
        if (MORE) {                                                              \
            gload_lds16(pB0 + (TOFF), dBase + 65536 + ((P)^1)*32768 + 0);        \
            gload_lds16(pB1 + (TOFF), dBase + 65536 + ((P)^1)*32768 + 16384);    \
            asm volatile("s_waitcnt vmcnt(4)" ::: "memory");                     \
        } else {                                                                 \
            asm volatile("s_waitcnt vmcnt(0)" ::: "memory");                     \
        }                                                                        \
        BAR();                                                                   \
        mfma16(4);                                                               \
        BAR();                                                                   \
        /* P3: (mf4-7, kq1); stage T+1.A.k1 */                                   \
        RD_A(P, 1, 4);                                                           \
        RD_B(P, 1);                                                              \
        if (MORE) { gload_lds16(pA0 + (TOFF) + 32, dBase + ((P)^1)*32768 + 8192);  \
                    gload_lds16(pA1 + (TOFF) + 32, dBase + ((P)^1)*32768 + 24576);} \
        BAR();                                                                   \
        mfma16(4);                                                               \
        BAR();                                                                   \
        /* P4: (mf0-3, kq1); stage T+1.B.k1; wait covers T+1.k0 planes */        \
        RD_A(P, 1, 0);                                                           \
        if (MORE) {                                                              \
            gload_lds16(pB0 + (TOFF) + 32, dBase + 65536 + ((P)^1)*32768 + 8192);  \
            gload_lds16(pB1 + (TOFF) + 32, dBase + 65536 + ((P)^1)*32768 + 24576); \
            asm volatile("s_waitcnt vmcnt(4)" ::: "memory");                     \
        }                                                                        \
        BAR();                                                                   \
        mfma16(0);                                                               \
        BAR();                                                                   \
    } while (0)

    #pragma unroll 1
    for (int T = 0; T < NT - 2; T += 2) {
        TILE(0, true, 0);
        TILE(1, true, 64);
        pA0 += 128; pA1 += 128; pB0 += 128; pB1 += 128;
    }
    TILE(0, true, 0);     // T = NT-2 (stages NT-1 from pA*+0: ptrs advanced (NT-2)/2 times)
    TILE(1, false, 64);   // T = NT-1 (drain at P2)

    // LoRA tail: one 32-wide K-step from TW [rows][32] / Bepi [cols][32].
    // Parity-0 chunks (last tile was parity 1). Reads = RD_A/RD_B with P=0,KQ=0.
    {
        stage_chunk32(TWb + (size_t)row0 * 32,          lds + 0,             t);
        stage_chunk32(TWb + (size_t)(row0 + 128) * 32,  lds + 16384,         t);
        stage_chunk32(Bepi + (size_t)col0 * 32,         lds + 65536,         t);
        stage_chunk32(Bepi + (size_t)(col0 + 128) * 32, lds + 65536 + 16384, t);
        asm volatile("s_waitcnt vmcnt(0)" ::: "memory");
        __builtin_amdgcn_s_barrier();
        RD_B(0, 0);
        RD_A(0, 0, 0);
        mfma16(0);
        RD_A(0, 0, 4);
        mfma16(4);
    }

    // Epilogue (direct stores, known correct): bias + relu, bf16.
    const int orow = row0 + wm * 128 + (lane >> 4) * 4;
    const int ocol = col0 + wn * 64 + r15;
    #pragma unroll
    for (int nf = 0; nf < 4; ++nf) {
        const int col = ocol + nf * 16;
        const float bn = bias[col];
        #pragma unroll
        for (int mf = 0; mf < 8; ++mf) {
            const int rbase = orow + mf * 16;
            #pragma unroll
            for (int i = 0; i < 4; ++i) {
                const float v = fmaxf(acc[mf][nf][i] + bn, 0.f);
                outp[(size_t)(rbase + i) * N + col] = (__bf16)v;
            }
        }
    }
    #undef TILE
    #undef RD_A
    #undef RD_B
    #undef BAR
}

// ---------------- old 128x128 GEMM (layer 3: N=512), now compile-time K
#define BM 128
#define BN 128
#define BK 32

template<bool OUT_F32, int K>
__global__ void __launch_bounds__(256) gemm_lora(
    const bf16_t* __restrict__ Abuf, const bf16_t* __restrict__ Wbuf,
    const float* __restrict__ bias, const bf16_t* __restrict__ TWb,
    const bf16_t* __restrict__ Bepi, void* __restrict__ outp,
    const int N)
{
    __shared__ bf16_t lA[BM * BK];
    __shared__ bf16_t lB[BN * BK];
    const int t = threadIdx.x;
    const int row0 = blockIdx.y * BM;
    const int col0 = blockIdx.x * BN;
    const int wid = t >> 6, lane = t & 63;
    const int wr = wid >> 1, wc = wid & 1;
    const int ln15 = lane & 15, kg = (lane >> 4) * 8;
    const int srow = t >> 2, sg8 = (t & 3) * 8;
    const bf16_t* gA = Abuf + (size_t)(row0 + srow) * K + sg8;
    const bf16_t* gB = Wbuf + (size_t)(col0 + srow) * K + sg8;
    bf16_t* ldA  = &lA[t * 8];
    bf16_t* ldA2 = &lA[2048 + t * 8];
    bf16_t* ldB  = &lB[t * 8];
    bf16_t* ldB2 = &lB[2048 + t * 8];
    f32x4 acc[4][4] = {};
    const int aoff = (wr * 64 + ln15) * BK + kg;
    const int boff = (wc * 64 + ln15) * BK + kg;

    auto compute_tile = [&]() {
        bf16x8 af[4], bfr[4];
        #pragma unroll
        for (int m = 0; m < 4; ++m) af[m] = *(const bf16x8*)&lA[aoff + m * 16 * BK];
        #pragma unroll
        for (int n = 0; n < 4; ++n) bfr[n] = *(const bf16x8*)&lB[boff + n * 16 * BK];
        #pragma unroll
        for (int m = 0; m < 4; ++m)
            #pragma unroll
            for (int n = 0; n < 4; ++n)
                acc[m][n] = __builtin_amdgcn_mfma_f32_16x16x32_bf16(af[m], bfr[n], acc[m][n], 0, 0, 0);
    };

    constexpr size_t half = (size_t)64 * K;
    constexpr int nk = K / BK;
    #pragma unroll 1
    for (int kt = 0; kt < nk; ++kt) {
        gload_lds16(gA + kt * BK, ldA);
        gload_lds16(gA + half + kt * BK, ldA2);
        gload_lds16(gB + kt * BK, ldB);
        gload_lds16(gB + half + kt * BK, ldB2);
        __syncthreads();
        compute_tile();
        __syncthreads();
    }
    gload_lds16(TWb + (size_t)(row0 + srow) * 32 + sg8, ldA);
    gload_lds16(TWb + (size_t)(row0 + 64 + srow) * 32 + sg8, ldA2);
    gload_lds16(Bepi + (size_t)(col0 + srow) * 32 + sg8, ldB);
    gload_lds16(Bepi + (size_t)(col0 + 64 + srow) * 32 + sg8, ldB2);
    __syncthreads();
    compute_tile();

    const int orow = row0 + wr * 64 + (lane >> 4) * 4;
    const int ocol = col0 + wc * 64 + ln15;
    #pragma unroll
    for (int n = 0; n < 4; ++n) {
        const int col = ocol + n * 16;
        const float bn = bias[col];
        #pragma unroll
        for (int m = 0; m < 4; ++m) {
            const int rbase = orow + m * 16;
            #pragma unroll
            for (int i = 0; i < 4; ++i) {
                const float v = fmaxf(acc[m][n][i] + bn, 0.f);
                if constexpr (OUT_F32)
                    ((float*)outp)[(size_t)(rbase + i) * N + col] = v;
                else
                    ((bf16_t*)outp)[(size_t)(rbase + i) * N + col] = (__bf16)v;
            }
        }
    }
}

extern "C" void kernel_launch(void* const* d_in, const int* in_sizes, int n_in,
                              void* d_out, int out_size, void* d_ws, size_t ws_size,
                              hipStream_t stream)
{
    const float* x    = (const float*)d_in[0];
    const int*   dom  = (const int*)d_in[1];
    const float* W1   = (const float*)d_in[2];  const float* b1  = (const float*)d_in[3];
    const float* W2   = (const float*)d_in[4];  const float* b2  = (const float*)d_in[5];
    const float* W3   = (const float*)d_in[6];  const float* b3  = (const float*)d_in[7];
    const float* A1   = (const float*)d_in[8];  const float* B1  = (const float*)d_in[9];
    const float* A2   = (const float*)d_in[10]; const float* B2  = (const float*)d_in[11];
    const float* A3   = (const float*)d_in[12]; const float* B3  = (const float*)d_in[13];
    const float* dome = (const float*)d_in[14]; const float* lpos = (const float*)d_in[15];
    const float* Wi1  = (const float*)d_in[16]; const float* bi1 = (const float*)d_in[17];
    const float* Wi2  = (const float*)d_in[18]; const float* bi2 = (const float*)d_in[19];
    const float* Wa1  = (const float*)d_in[20]; const float* ba1 = (const float*)d_in[21];
    const float* Wa2  = (const float*)d_in[22]; const float* ba2 = (const float*)d_in[23];
    const float* gate = (const float*)d_in[24]; const float* Rb  = (const float*)d_in[25];
    (void)in_sizes; (void)n_in; (void)out_size; (void)ws_size;

    constexpr int Bsz = 16384, D0 = 2048, D1 = 2048, D2 = 1024, D3 = 512;

    char* ws = (char*)d_ws;
    size_t off = 0;
    auto alloc = [&](size_t bytes) -> void* {
        void* p = ws + off;
        off = (off + bytes + 255) & ~(size_t)255;
        return p;
    };
    float*  salpha = (float*) alloc(8 * 3 * 4 * sizeof(float));
    bf16_t* W1b = (bf16_t*)alloc((size_t)D1 * D0 * 2);
    bf16_t* W2b = (bf16_t*)alloc((size_t)D2 * D1 * 2);
    bf16_t* W3b = (bf16_t*)alloc((size_t)D3 * D2 * 2);
    bf16_t* Ac1 = (bf16_t*)alloc((size_t)32 * D0 * 2);
    bf16_t* Ac2 = (bf16_t*)alloc((size_t)32 * D1 * 2);
    bf16_t* Ac3 = (bf16_t*)alloc((size_t)32 * D2 * 2);
    bf16_t* Be1 = (bf16_t*)alloc((size_t)D1 * 32 * 2);
    bf16_t* Be2 = (bf16_t*)alloc((size_t)D2 * 32 * 2);
    bf16_t* Be3 = (bf16_t*)alloc((size_t)D3 * 32 * 2);
    bf16_t* TWb = (bf16_t*)alloc((size_t)Bsz * 32 * 2);
    bf16_t* xb  = (bf16_t*)alloc((size_t)Bsz * D0 * 2);
    bf16_t* h1b = (bf16_t*)alloc((size_t)Bsz * D1 * 2);
    bf16_t* h2b = xb;  // xb dead after layer-1 GEMM

    routing_kernel<<<1, 256, 0, stream>>>(dome, lpos, Wi1, bi1, Wi2, bi2,
                                          Wa1, ba1, Wa2, ba2, gate, Rb, salpha);

    cvt_fused<<<6816, 256, 0, stream>>>(W1, W2, W3, A1, A2, A3, W1b);
    bepi_fused<<<448, 256, 0, stream>>>(B1, B2, B3, Be1);

    // layer 1: K = D0 = 2048, N = D1 = 2048 (grid 512)
    tw_kernel<true><<<Bsz / 64, 256, 0, stream>>>(x, xb, Ac1, salpha, dom, 0, D0, TWb);
    gemm_lora8<2048><<<(Bsz / 256) * (D1 / 256), 512, 0, stream>>>(xb, W1b, b1, TWb, Be1, h1b, D1, D1 / 256);
    // layer 2: K = D1 = 2048 (reduction dim), N = D2 = 1024 (grid 256)
    tw_kernel<false><<<Bsz / 64, 256, 0, stream>>>(h1b, nullptr, Ac2, salpha, dom, 1, D1, TWb);
    gemm_lora8<2048><<<(Bsz / 256) * (D2 / 256), 512, 0, stream>>>(h1b, W2b, b2, TWb, Be2, h2b, D2, D2 / 256);
    // layer 3 (f32 out, 128^2 kernel): K = D2 = 1024
    tw_kernel<false><<<Bsz / 64, 256, 0, stream>>>(h2b, nullptr, Ac3, salpha, dom, 2, D2, TWb);
    gemm_lora<true, 1024><<<dim3(D3 / BN, Bsz / BM), 256, 0, stream>>>(h2b, W3b, b3, TWb, Be3, d_out, D3);
}

// Round 12
// 392.985 us; speedup vs baseline: 1.0327x; 1.0327x over previous
//
#include <hip/hip_runtime.h>

typedef __bf16 bf16_t;
typedef __bf16 bf16x8 __attribute__((ext_vector_type(8)));
typedef __bf16 bf16x4_v __attribute__((ext_vector_type(4)));
typedef float f32x4 __attribute__((ext_vector_type(4)));

#define AS1 __attribute__((address_space(1)))
#define AS3 __attribute__((address_space(3)))

__device__ __forceinline__ void gload_lds16(const void* g, void* l) {
    __builtin_amdgcn_global_load_lds((AS1 void*)(void*)g, (AS3 void*)l, 16, 0, 0);
}

// ---------------- routing: salpha[m][l][e] = zeta_agg[m][l] * alpha_agg[m][l][e]
__global__ void routing_kernel(
    const float* __restrict__ dom_emb, const float* __restrict__ layer_pos,
    const float* __restrict__ Wi1, const float* __restrict__ bi1,
    const float* __restrict__ Wi2, const float* __restrict__ bi2,
    const float* __restrict__ Wa1, const float* __restrict__ ba1,
    const float* __restrict__ Wa2, const float* __restrict__ ba2,
    const float* __restrict__ gate_logits, const float* __restrict__ R_benefit,
    float* __restrict__ salpha)
{
    constexpr int M = 8, L = 3, E = 4, H = 64;
    __shared__ float zl[M * L];
    __shared__ float al[M * L][E];
    __shared__ float zeta_all[M][L];
    __shared__ float alpha_all[M][L][E];
    const int t = threadIdx.x;
    const int ml = t >> 3, js = t & 7;
    if (ml < M * L) {
        const int m = ml / L, l = ml % L;
        float zacc = 0.f;
        float aacc[E] = {0.f, 0.f, 0.f, 0.f};
        for (int jj = 0; jj < 8; ++jj) {
            const int j = js * 8 + jj;
            float hz = bi1[j], ha = ba1[j];
            for (int i = 0; i < H; ++i) {
                const float de = dom_emb[m * H + i];
                const float lp = layer_pos[l * H + i];
                hz += de * Wi1[j * 2 * H + i] + lp * Wi1[j * 2 * H + H + i];
                ha += de * Wa1[j * 2 * H + i] + lp * Wa1[j * 2 * H + H + i];
            }
            hz = fmaxf(hz, 0.f); ha = fmaxf(ha, 0.f);
            zacc += hz * Wi2[j];
            for (int e = 0; e < E; ++e) aacc[e] += ha * Wa2[e * H + j];
        }
        #pragma unroll
        for (int off = 4; off >= 1; off >>= 1) {
            zacc += __shfl_down(zacc, off, 8);
            for (int e = 0; e < E; ++e) aacc[e] += __shfl_down(aacc[e], off, 8);
        }
        if (js == 0) {
            zl[ml] = zacc + bi2[0];
            for (int e = 0; e < E; ++e) al[ml][e] = aacc[e] + ba2[e];
        }
    }
    __syncthreads();
    if (t < M) {
        const int m = t;
        float v[3] = { zl[m * L + 0], zl[m * L + 1], zl[m * L + 2] };
        int di = 0; float dv = v[0];
        for (int i = 1; i < 3; ++i) if (v[i] <= dv) { dv = v[i]; di = i; }
        float mx = -1e30f;
        for (int i = 0; i < 3; ++i) if (i != di) mx = fmaxf(mx, v[i]);
        float s = 0.f, ev[3];
        for (int i = 0; i < 3; ++i) { ev[i] = (i == di) ? 0.f : expf(v[i] - mx); s += ev[i]; }
        for (int i = 0; i < 3; ++i) zeta_all[m][i] = ev[i] / s;
        for (int l = 0; l < L; ++l) {
            float a[4];
            for (int e = 0; e < 4; ++e) a[e] = al[m * L + l][e];
            int i1 = 0;
            for (int e = 1; e < 4; ++e) if (a[e] > a[i1]) i1 = e;
            int i2 = -1;
            for (int e = 0; e < 4; ++e) { if (e == i1) continue; if (i2 < 0 || a[e] > a[i2]) i2 = e; }
            const float mx2 = fmaxf(a[i1], a[i2]);
            const float e1 = expf(a[i1] - mx2), e2 = expf(a[i2] - mx2);
            const float ss = e1 + e2;
            for (int e = 0; e < 4; ++e) alpha_all[m][l][e] = 0.f;
            alpha_all[m][l][i1] = e1 / ss;
            alpha_all[m][l][i2] = e2 / ss;
        }
    }
    __syncthreads();
    if (t < M) {
        const int m = t;
        float Rrow[8]; float rs = 0.f;
        for (int n = 0; n < M; ++n) {
            const float g = gate_logits[m * M + n];
            const float rr = log1pf(expf(g)) * R_benefit[m * M + n];
            Rrow[n] = rr; rs += rr;
        }
        rs = fmaxf(rs, 1e-12f);
        for (int l = 0; l < L; ++l) {
            float zag = 0.f, aag[4] = {0.f, 0.f, 0.f, 0.f};
            for (int n = 0; n < M; ++n) {
                const float w = Rrow[n] / rs;
                zag += w * zeta_all[n][l];
                for (int e = 0; e < 4; ++e) aag[e] += w * alpha_all[n][l][e];
            }
            for (int e = 0; e < 4; ++e) salpha[(m * L + l) * 4 + e] = zag * aag[e];
        }
    }
}

// ---------------- fused f32->bf16 convert: W1,W2,W3,A1,A2,A3 into contiguous dst
__global__ void cvt_fused(const float* __restrict__ s0, const float* __restrict__ s1,
                          const float* __restrict__ s2, const float* __restrict__ s3,
                          const float* __restrict__ s4, const float* __restrict__ s5,
                          bf16_t* __restrict__ dst)
{
    const int i = blockIdx.x * 256 + threadIdx.x;   // float4 index
    constexpr int b0 = 1048576;
    constexpr int b1 = b0 + 524288;
    constexpr int b2 = b1 + 131072;
    constexpr int b3 = b2 + 16384;
    constexpr int b4 = b3 + 16384;
    constexpr int b5 = b4 + 8192;
    if (i >= b5) return;
    const float* src; int rel;
    if (i < b0)      { src = s0; rel = i; }
    else if (i < b1) { src = s1; rel = i - b0; }
    else if (i < b2) { src = s2; rel = i - b1; }
    else if (i < b3) { src = s3; rel = i - b2; }
    else if (i < b4) { src = s4; rel = i - b3; }
    else             { src = s5; rel = i - b4; }
    const float4 v = ((const float4*)src)[rel];
    bf16x4_v o;
    o[0] = (__bf16)v.x; o[1] = (__bf16)v.y; o[2] = (__bf16)v.z; o[3] = (__bf16)v.w;
    ((bf16x4_v*)dst)[i] = o;
}

// ---------------- fused Bepi pack: B [E][Dout][r] f32 -> [Dout][32] bf16, c=e*8+r
__global__ void bepi_fused(const float* __restrict__ B1, const float* __restrict__ B2,
                           const float* __restrict__ B3, bf16_t* __restrict__ dst)
{
    const int idx = blockIdx.x * 256 + threadIdx.x;
    constexpr int c1 = 2048 * 32, c2 = c1 + 1024 * 32, c3 = c2 + 512 * 32;
    if (idx >= c3) return;
    const float* B; int rel, Dout;
    if (idx < c1)      { B = B1; rel = idx;      Dout = 2048; }
    else if (idx < c2) { B = B2; rel = idx - c1; Dout = 1024; }
    else               { B = B3; rel = idx - c2; Dout = 512; }
    const int o = rel >> 5, c = rel & 31, e = c >> 3, r = c & 7;
    dst[idx] = (__bf16)B[((size_t)e * Dout + o) * 8 + r];
}

// ---------------- TW[b][c] = (sum_k h[b][k]*Acat[c][k]) * salpha[dom[b]][layer][c>>3]
// R12: 2-way K-split ILP — tw launches only 1024 waves (1/SIMD, no TLP), so
// HBM latency was nearly bare. 4 independent MFMA chains + 4 loads in flight
// per iter halves the latency-exposed iteration count.
template<bool F32IN>
__global__ void __launch_bounds__(256) tw_kernel(
    const void* __restrict__ hin, bf16_t* __restrict__ xb_out,
    const bf16_t* __restrict__ Acat, const float* __restrict__ salpha,
    const int* __restrict__ dom, const int layer, const int K,
    bf16_t* __restrict__ TWb)
{
    const int t = threadIdx.x, wid = t >> 6, lane = t & 63;
    const int rb = blockIdx.x * 64 + wid * 16;
    const int ln15 = lane & 15, kg = (lane >> 4) * 8;
    const int row = rb + ln15;
    const int Kh = K >> 1;
    f32x4 a0l = {0.f,0.f,0.f,0.f}, a1l = {0.f,0.f,0.f,0.f};
    f32x4 a0h = {0.f,0.f,0.f,0.f}, a1h = {0.f,0.f,0.f,0.f};
    const bf16_t* pa0 = Acat + (size_t)ln15 * K + kg;
    const bf16_t* pa1 = pa0 + (size_t)16 * K;
    for (int k0 = 0; k0 < Kh; k0 += 32) {
        bf16x8 al, ah;
        if constexpr (F32IN) {
            const float* px = (const float*)hin + (size_t)row * K + k0 + kg;
            const float4 x0 = *(const float4*)px;
            const float4 x1 = *(const float4*)(px + 4);
            const float4 y0 = *(const float4*)(px + Kh);
            const float4 y1 = *(const float4*)(px + Kh + 4);
            al[0] = (__bf16)x0.x; al[1] = (__bf16)x0.y; al[2] = (__bf16)x0.z; al[3] = (__bf16)x0.w;
            al[4] = (__bf16)x1.x; al[5] = (__bf16)x1.y; al[6] = (__bf16)x1.z; al[7] = (__bf16)x1.w;
            ah[0] = (__bf16)y0.x; ah[1] = (__bf16)y0.y; ah[2] = (__bf16)y0.z; ah[3] = (__bf16)y0.w;
            ah[4] = (__bf16)y1.x; ah[5] = (__bf16)y1.y; ah[6] = (__bf16)y1.z; ah[7] = (__bf16)y1.w;
            *(bf16x8*)(xb_out + (size_t)row * K + k0 + kg) = al;
            *(bf16x8*)(xb_out + (size_t)row * K + Kh + k0 + kg) = ah;
        } else {
            al = *(const bf16x8*)((const bf16_t*)hin + (size_t)row * K + k0 + kg);
            ah = *(const bf16x8*)((const bf16_t*)hin + (size_t)row * K + Kh + k0 + kg);
        }
        const bf16x8 b0l = *(const bf16x8*)(pa0 + k0);
        const bf16x8 b1l = *(const bf16x8*)(pa1 + k0);
        const bf16x8 b0h = *(const bf16x8*)(pa0 + Kh + k0);
        const bf16x8 b1h = *(const bf16x8*)(pa1 + Kh + k0);
        a0l = __builtin_amdgcn_mfma_f32_16x16x32_bf16(al, b0l, a0l, 0, 0, 0);
        a1l = __builtin_amdgcn_mfma_f32_16x16x32_bf16(al, b1l, a1l, 0, 0, 0);
        a0h = __builtin_amdgcn_mfma_f32_16x16x32_bf16(ah, b0h, a0h, 0, 0, 0);
        a1h = __builtin_amdgcn_mfma_f32_16x16x32_bf16(ah, b1h, a1h, 0, 0, 0);
    }
    const f32x4 acc0 = a0l + a0h;   // disjoint K-ranges: partial sums add
    const f32x4 acc1 = a1l + a1h;
    const int rbase = rb + (lane >> 4) * 4;
    #pragma unroll
    for (int i = 0; i < 4; ++i) {
        const int r2 = rbase + i;
        const int d = dom[r2];
        const float* sa = salpha + (d * 3 + layer) * 4;
        const float s0 = sa[ln15 >> 3];
        const float s1 = sa[2 + (ln15 >> 3)];
        TWb[(size_t)r2 * 32 + ln15]      = (__bf16)(acc0[i] * s0);
        TWb[(size_t)r2 * 32 + 16 + ln15] = (__bf16)(acc1[i] * s1);
    }
}

// ================= 256x256 8-phase GEMM + fused LoRA K-step =================
// LDS chunk = 16KB = [kh:2][row:128][32 k] bf16, 64B rows; swizzle: 16B-slot
// bit1 ^= row bit3 (R5-verified conflict-free, SQ_LDS_BANK_CONFLICT=0).
// R12: ONE barrier per phase (ENDBAR removed; was 8 barriers/K-tile, ~13% of
// tile time). Race ledger: stage-completeness gate = own-wave vmcnt + the
// pre-MFMA barrier (unchanged). Overwrite hazard: a reading wave drains lgkm
// before its phase-X MFMA, hence before passing barrier X; every plane's
// stage-issue is >= 3 phases after its last read (A.k0: read T.P2, staged
// T+1.P1 -> 3 barriers; A.k1: T.P4 -> T+1.P3; B.k0: T.P3 -> T+1.P2;
// B.k1: T.P3 -> T+1.P4). Prologue ordering unchanged.
// Schedule: plane staging P1:A.k0 P2:B.k0 P3:A.k1 P4:B.k1 for T+1;
// vmcnt(4) at P2/P4; drain at last tile's P2. Template<int K> 2-tile unroll.

__device__ __forceinline__ void stage_chunk32(const bf16_t* g, char* chunk, int t) {
    const int row = t >> 2;
    const int sl = t & 3;
    const int src = sl ^ (((row >> 3) & 1) << 1);
    gload_lds16(g + (size_t)row * 32 + src * 8, chunk + t * 16);
}

template<int K>
__global__ void __launch_bounds__(512, 2) gemm_lora8(
    const bf16_t* __restrict__ Abuf, const bf16_t* __restrict__ Wbuf,
    const float* __restrict__ bias, const bf16_t* __restrict__ TWb,
    const bf16_t* __restrict__ Bepi, bf16_t* __restrict__ outp,
    const int N, const int nwg_n)
{
    __shared__ __align__(1024) char lds[131072];
    const int t = threadIdx.x;
    const int wid = t >> 6, lane = t & 63;
    const int wm = wid >> 2, wn = wid & 3, wnh = wn >> 1;
    const int cpx = gridDim.x >> 3;
    const int wg = (blockIdx.x & 7) * cpx + (blockIdx.x >> 3);
    const int row0 = (wg / nwg_n) * 256, col0 = (wg % nwg_n) * 256;

    const int r15 = lane & 15;
    const int swb = ((lane >> 4) ^ (((lane >> 3) & 1) << 1)) << 4;

    // canonical per-wave LDS read bases
    const char* aBase = lds + (wm << 14) + (r15 << 6) + swb;
    const char* bBase = lds + 65536 + (wnh << 14) + ((wn & 1) << 12) + (r15 << 6) + swb;
    char* const dBase = lds + t * 16;

    // staging source ptrs (inverse-swizzled slot)
    const int srow = t >> 2, ssl = t & 3;
    const int ssrc = ssl ^ (((srow >> 3) & 1) << 1);
    const bf16_t* sA = Abuf + (size_t)(row0 + srow) * K + ssrc * 8;
    const bf16_t* sB = Wbuf + (size_t)(col0 + srow) * K + ssrc * 8;
    constexpr size_t halfA = (size_t)128 * K;

    f32x4 acc[8][4] = {};
    bf16x8 aF[4], bF[4];

    #define RD_A(P, KQ, MB) do { _Pragma("unroll") for (int i_ = 0; i_ < 4; ++i_) \
        aF[i_] = *(const bf16x8*)(aBase + (P)*32768 + (KQ)*8192 + ((MB)+i_)*1024); } while (0)
    #define RD_B(P, KQ) do { _Pragma("unroll") for (int n_ = 0; n_ < 4; ++n_) \
        bF[n_] = *(const bf16x8*)(bBase + (P)*32768 + (KQ)*8192 + n_*1024); } while (0)

    auto mfma16 = [&](int mbase) {
        __builtin_amdgcn_s_setprio(1);
        #pragma unroll
        for (int mf = 0; mf < 4; ++mf)
            #pragma unroll
            for (int nf = 0; nf < 4; ++nf)
                acc[mbase + mf][nf] =
                    __builtin_amdgcn_mfma_f32_16x16x32_bf16(aF[mf], bF[nf], acc[mbase + mf][nf], 0, 0, 0);
        __builtin_amdgcn_s_setprio(0);
    };
    #define BAR() __builtin_amdgcn_s_barrier()

    constexpr int NT = K >> 6;   // even, >= 16

    // Prologue: T0 planes in chain order {A.k0, B.k0, A.k1, B.k1} (parity 0)
    gload_lds16(sA,              dBase + 0);
    gload_lds16(sA + halfA,      dBase + 16384);
    gload_lds16(sB,              dBase + 65536);
    gload_lds16(sB + halfA,      dBase + 65536 + 16384);
    gload_lds16(sA + 32,         dBase + 8192);
    gload_lds16(sA + halfA + 32, dBase + 24576);
    gload_lds16(sB + 32,         dBase + 65536 + 8192);
    gload_lds16(sB + halfA + 32, dBase + 65536 + 24576);
    asm volatile("s_waitcnt vmcnt(4)" ::: "memory");
    __builtin_amdgcn_s_barrier();

    const bf16_t* pA0 = sA + 64;
    const bf16_t* pA1 = sA + halfA + 64;
    const bf16_t* pB0 = sB + 64;
    const bf16_t* pB1 = sB + halfA + 64;

    // One K-tile, ONE barrier per phase (pre-MFMA). Reads -> stages -> [vmcnt]
    // -> BAR -> MFMA.
    #define TILE(P, MORE, TOFF) do {                                            \
        /* P1: (mf0-3, kq0); stage T+1.A.k0 */                                   \
        RD_A(P, 0, 0);                                                           \
        RD_B(P, 0);                                                              \
        if (MORE) { gload_lds16(pA0 + (TOFF), dBase + ((P)^1)*32768 + 0);        \
                    gload_lds16(pA1 + (TOFF), dBase + ((P)^1)*32768 + 16384); }  \
        BAR();                                                                   \
        mfma16(0);                                                               \
        /* P2: (mf4-7, kq0); stage T+1.B.k0; wait covers T.k1 planes */          \
        RD_A(P, 0, 4);                                                           \
        if (MORE) {                                                              \
            gload_lds16(pB0 + (TOFF), dBase + 65536 + ((P)^1)*32768 + 0);        \
            gload_lds16(pB1 + (TOFF), dBase + 65536 + ((P)^1)*32768 + 16384);    \
            asm volatile("s_waitcnt vmcnt(4)" ::: "memory");                     \
        } else {                                                                 \
            asm volatile("s_waitcnt vmcnt(0)" ::: "memory");                     \
        }                                                                        \
        BAR();                                                                   \
        mfma16(4);                                                               \
        /* P3: (mf4-7, kq1); stage T+1.A.k1 */                                   \
        RD_A(P, 1, 4);                                                           \
        RD_B(P, 1);                                                              \
        if (MORE) { gload_lds16(pA0 + (TOFF) + 32, dBase + ((P)^1)*32768 + 8192);  \
                    gload_lds16(pA1 + (TOFF) + 32, dBase + ((P)^1)*32768 + 24576);} \
        BAR();                                                                   \
        mfma16(4);                                                               \
        /* P4: (mf0-3, kq1); stage T+1.B.k1; wait covers T+1.k0 planes */        \
        RD_A(P, 1, 0);                                                           \
        if (MORE) {                                                              \
            gload_lds16(pB0 + (TOFF) + 32, dBase + 65536 + ((P)^1)*32768 + 8192);  \
            gload_lds16(pB1 + (TOFF) + 32, dBase + 65536 + ((P)^1)*32768 + 24576); \
            asm volatile("s_waitcnt vmcnt(4)" ::: "memory");                     \
        }                                                                        \
        BAR();                                                                   \
        mfma16(0);                                                               \
    } while (0)

    #pragma unroll 1
    for (int T = 0; T < NT - 2; T += 2) {
        TILE(0, true, 0);
        TILE(1, true, 64);
        pA0 += 128; pA1 += 128; pB0 += 128; pB1 += 128;
    }
    TILE(0, true, 0);     // T = NT-2
    TILE(1, false, 64);   // T = NT-1 (drain at P2)

    // LoRA tail: parity-0 chunks (last tile was parity 1). Barrier first so
    // stage-writes can't race the final phase's reads (which drained before
    // the last MFMA's lgkm wait; this barrier orders all waves past it).
    {
        __builtin_amdgcn_s_barrier();
        stage_chunk32(TWb + (size_t)row0 * 32,          lds + 0,             t);
        stage_chunk32(TWb + (size_t)(row0 + 128) * 32,  lds + 16384,         t);
        stage_chunk32(Bepi + (size_t)col0 * 32,         lds + 65536,         t);
        stage_chunk32(Bepi + (size_t)(col0 + 128) * 32, lds + 65536 + 16384, t);
        asm volatile("s_waitcnt vmcnt(0)" ::: "memory");
        __builtin_amdgcn_s_barrier();
        RD_B(0, 0);
        RD_A(0, 0, 0);
        mfma16(0);
        RD_A(0, 0, 4);
        mfma16(4);
    }

    // Epilogue (direct stores, known correct): bias + relu, bf16.
    const int orow = row0 + wm * 128 + (lane >> 4) * 4;
    const int ocol = col0 + wn * 64 + r15;
    #pragma unroll
    for (int nf = 0; nf < 4; ++nf) {
        const int col = ocol + nf * 16;
        const float bn = bias[col];
        #pragma unroll
        for (int mf = 0; mf < 8; ++mf) {
            const int rbase = orow + mf * 16;
            #pragma unroll
            for (int i = 0; i < 4; ++i) {
                const float v = fmaxf(acc[mf][nf][i] + bn, 0.f);
                outp[(size_t)(rbase + i) * N + col] = (__bf16)v;
            }
        }
    }
    #undef TILE
    #undef RD_A
    #undef RD_B
    #undef BAR
}

// ---------------- old 128x128 GEMM (layer 3: N=512), compile-time K
#define BM 128
#define BN 128
#define BK 32

template<bool OUT_F32, int K>
__global__ void __launch_bounds__(256) gemm_lora(
    const bf16_t* __restrict__ Abuf, const bf16_t* __restrict__ Wbuf,
    const float* __restrict__ bias, const bf16_t* __restrict__ TWb,
    const bf16_t* __restrict__ Bepi, void* __restrict__ outp,
    const int N)
{
    __shared__ bf16_t lA[BM * BK];
    __shared__ bf16_t lB[BN * BK];
    const int t = threadIdx.x;
    const int row0 = blockIdx.y * BM;
    const int col0 = blockIdx.x * BN;
    const int wid = t >> 6, lane = t & 63;
    const int wr = wid >> 1, wc = wid & 1;
    const int ln15 = lane & 15, kg = (lane >> 4) * 8;
    const int srow = t >> 2, sg8 = (t & 3) * 8;
    const bf16_t* gA = Abuf + (size_t)(row0 + srow) * K + sg8;
    const bf16_t* gB = Wbuf + (size_t)(col0 + srow) * K + sg8;
    bf16_t* ldA  = &lA[t * 8];
    bf16_t* ldA2 = &lA[2048 + t * 8];
    bf16_t* ldB  = &lB[t * 8];
    bf16_t* ldB2 = &lB[2048 + t * 8];
    f32x4 acc[4][4] = {};
    const int aoff = (wr * 64 + ln15) * BK + kg;
    const int boff = (wc * 64 + ln15) * BK + kg;

    auto compute_tile = [&]() {
        bf16x8 af[4], bfr[4];
        #pragma unroll
        for (int m = 0; m < 4; ++m) af[m] = *(const bf16x8*)&lA[aoff + m * 16 * BK];
        #pragma unroll
        for (int n = 0; n < 4; ++n) bfr[n] = *(const bf16x8*)&lB[boff + n * 16 * BK];
        #pragma unroll
        for (int m = 0; m < 4; ++m)
            #pragma unroll
            for (int n = 0; n < 4; ++n)
                acc[m][n] = __builtin_amdgcn_mfma_f32_16x16x32_bf16(af[m], bfr[n], acc[m][n], 0, 0, 0);
    };

    constexpr size_t half = (size_t)64 * K;
    constexpr int nk = K / BK;
    #pragma unroll 1
    for (int kt = 0; kt < nk; ++kt) {
        gload_lds16(gA + kt * BK, ldA);
        gload_lds16(gA + half + kt * BK, ldA2);
        gload_lds16(gB + kt * BK, ldB);
        gload_lds16(gB + half + kt * BK, ldB2);
        __syncthreads();
        compute_tile();
        __syncthreads();
    }
    gload_lds16(TWb + (size_t)(row0 + srow) * 32 + sg8, ldA);
    gload_lds16(TWb + (size_t)(row0 + 64 + srow) * 32 + sg8, ldA2);
    gload_lds16(Bepi + (size_t)(col0 + srow) * 32 + sg8, ldB);
    gload_lds16(Bepi + (size_t)(col0 + 64 + srow) * 32 + sg8, ldB2);
    __syncthreads();
    compute_tile();

    const int orow = row0 + wr * 64 + (lane >> 4) * 4;
    const int ocol = col0 + wc * 64 + ln15;
    #pragma unroll
    for (int n = 0; n < 4; ++n) {
        const int col = ocol + n * 16;
        const float bn = bias[col];
        #pragma unroll
        for (int m = 0; m < 4; ++m) {
            const int rbase = orow + m * 16;
            #pragma unroll
            for (int i = 0; i < 4; ++i) {
                const float v = fmaxf(acc[m][n][i] + bn, 0.f);
                if constexpr (OUT_F32)
                    ((float*)outp)[(size_t)(rbase + i) * N + col] = v;
                else
                    ((bf16_t*)outp)[(size_t)(rbase + i) * N + col] = (__bf16)v;
            }
        }
    }
}

extern "C" void kernel_launch(void* const* d_in, const int* in_sizes, int n_in,
                              void* d_out, int out_size, void* d_ws, size_t ws_size,
                              hipStream_t stream)
{
    const float* x    = (const float*)d_in[0];
    const int*   dom  = (const int*)d_in[1];
    const float* W1   = (const float*)d_in[2];  const float* b1  = (const float*)d_in[3];
    const float* W2   = (const float*)d_in[4];  const float* b2  = (const float*)d_in[5];
    const float* W3   = (const float*)d_in[6];  const float* b3  = (const float*)d_in[7];
    const float* A1   = (const float*)d_in[8];  const float* B1  = (const float*)d_in[9];
    const float* A2   = (const float*)d_in[10]; const float* B2  = (const float*)d_in[11];
    const float* A3   = (const float*)d_in[12]; const float* B3  = (const float*)d_in[13];
    const float* dome = (const float*)d_in[14]; const float* lpos = (const float*)d_in[15];
    const float* Wi1  = (const float*)d_in[16]; const float* bi1 = (const float*)d_in[17];
    const float* Wi2  = (const float*)d_in[18]; const float* bi2 = (const float*)d_in[19];
    const float* Wa1  = (const float*)d_in[20]; const float* ba1 = (const float*)d_in[21];
    const float* Wa2  = (const float*)d_in[22]; const float* ba2 = (const float*)d_in[23];
    const float* gate = (const float*)d_in[24]; const float* Rb  = (const float*)d_in[25];
    (void)in_sizes; (void)n_in; (void)out_size; (void)ws_size;

    constexpr int Bsz = 16384, D0 = 2048, D1 = 2048, D2 = 1024, D3 = 512;

    char* ws = (char*)d_ws;
    size_t off = 0;
    auto alloc = [&](size_t bytes) -> void* {
        void* p = ws + off;
        off = (off + bytes + 255) & ~(size_t)255;
        return p;
    };
    float*  salpha = (float*) alloc(8 * 3 * 4 * sizeof(float));
    bf16_t* W1b = (bf16_t*)alloc((size_t)D1 * D0 * 2);
    bf16_t* W2b = (bf16_t*)alloc((size_t)D2 * D1 * 2);
    bf16_t* W3b = (bf16_t*)alloc((size_t)D3 * D2 * 2);
    bf16_t* Ac1 = (bf16_t*)alloc((size_t)32 * D0 * 2);
    bf16_t* Ac2 = (bf16_t*)alloc((size_t)32 * D1 * 2);
    bf16_t* Ac3 = (bf16_t*)alloc((size_t)32 * D2 * 2);
    bf16_t* Be1 = (bf16_t*)alloc((size_t)D1 * 32 * 2);
    bf16_t* Be2 = (bf16_t*)alloc((size_t)D2 * 32 * 2);
    bf16_t* Be3 = (bf16_t*)alloc((size_t)D3 * 32 * 2);
    bf16_t* TWb = (bf16_t*)alloc((size_t)Bsz * 32 * 2);
    bf16_t* xb  = (bf16_t*)alloc((size_t)Bsz * D0 * 2);
    bf16_t* h1b = (bf16_t*)alloc((size_t)Bsz * D1 * 2);
    bf16_t* h2b = xb;  // xb dead after layer-1 GEMM

    routing_kernel<<<1, 256, 0, stream>>>(dome, lpos, Wi1, bi1, Wi2, bi2,
                                          Wa1, ba1, Wa2, ba2, gate, Rb, salpha);

    cvt_fused<<<6816, 256, 0, stream>>>(W1, W2, W3, A1, A2, A3, W1b);
    bepi_fused<<<448, 256, 0, stream>>>(B1, B2, B3, Be1);

    // layer 1: K = D0 = 2048, N = D1 = 2048 (grid 512)
    tw_kernel<true><<<Bsz / 64, 256, 0, stream>>>(x, xb, Ac1, salpha, dom, 0, D0, TWb);
    gemm_lora8<2048><<<(Bsz / 256) * (D1 / 256), 512, 0, stream>>>(xb, W1b, b1, TWb, Be1, h1b, D1, D1 / 256);
    // layer 2: K = D1 = 2048 (reduction dim), N = D2 = 1024 (grid 256)
    tw_kernel<false><<<Bsz / 64, 256, 0, stream>>>(h1b, nullptr, Ac2, salpha, dom, 1, D1, TWb);
    gemm_lora8<2048><<<(Bsz / 256) * (D2 / 256), 512, 0, stream>>>(h1b, W2b, b2, TWb, Be2, h2b, D2, D2 / 256);
    // layer 3 (f32 out, 128^2 kernel): K = D2 = 1024
    tw_kernel<false><<<Bsz / 64, 256, 0, stream>>>(h2b, nullptr, Ac3, salpha, dom, 2, D2, TWb);
    gemm_lora<true, 1024><<<dim3(D3 / BN, Bsz / BM), 256, 0, stream>>>(h2b, W3b, b3, TWb, Be3, d_out, D3);
}

// Round 13
// 370.012 us; speedup vs baseline: 1.0968x; 1.0621x over previous
//
#include <hip/hip_runtime.h>

typedef __bf16 bf16_t;
typedef __bf16 bf16x8 __attribute__((ext_vector_type(8)));
typedef __bf16 bf16x4_v __attribute__((ext_vector_type(4)));
typedef float f32x4 __attribute__((ext_vector_type(4)));

#define AS1 __attribute__((address_space(1)))
#define AS3 __attribute__((address_space(3)))

__device__ __forceinline__ void gload_lds16(const void* g, void* l) {
    __builtin_amdgcn_global_load_lds((AS1 void*)(void*)g, (AS3 void*)l, 16, 0, 0);
}

// ================= prep kernel: routing (block 0) + cvt (blocks 1..6816) +
// bepi pack (blocks 6817..7264) in ONE launch. All three are independent;
// merging hides the 1-block routing's serial time under cvt and saves 2
// launch gaps.
__global__ void __launch_bounds__(256) prep_kernel(
    // routing args
    const float* __restrict__ dom_emb, const float* __restrict__ layer_pos,
    const float* __restrict__ Wi1, const float* __restrict__ bi1,
    const float* __restrict__ Wi2, const float* __restrict__ bi2,
    const float* __restrict__ Wa1, const float* __restrict__ ba1,
    const float* __restrict__ Wa2, const float* __restrict__ ba2,
    const float* __restrict__ gate_logits, const float* __restrict__ R_benefit,
    float* __restrict__ salpha,
    // cvt args: W1,W2,W3,A1,A2,A3 -> contiguous bf16 dst
    const float* __restrict__ s0, const float* __restrict__ s1,
    const float* __restrict__ s2, const float* __restrict__ s3,
    const float* __restrict__ s4, const float* __restrict__ s5,
    bf16_t* __restrict__ wdst,
    // bepi args
    const float* __restrict__ B1, const float* __restrict__ B2,
    const float* __restrict__ B3, bf16_t* __restrict__ bedst)
{
    const int blk = blockIdx.x;
    const int t = threadIdx.x;
    if (blk == 0) {
        // ---- routing ----
        constexpr int M = 8, L = 3, E = 4, H = 64;
        __shared__ float zl[M * L];
        __shared__ float al[M * L][E];
        __shared__ float zeta_all[M][L];
        __shared__ float alpha_all[M][L][E];
        const int ml = t >> 3, js = t & 7;
        if (ml < M * L) {
            const int m = ml / L, l = ml % L;
            float zacc = 0.f;
            float aacc[E] = {0.f, 0.f, 0.f, 0.f};
            for (int jj = 0; jj < 8; ++jj) {
                const int j = js * 8 + jj;
                float hz = bi1[j], ha = ba1[j];
                for (int i = 0; i < H; ++i) {
                    const float de = dom_emb[m * H + i];
                    const float lp = layer_pos[l * H + i];
                    hz += de * Wi1[j * 2 * H + i] + lp * Wi1[j * 2 * H + H + i];
                    ha += de * Wa1[j * 2 * H + i] + lp * Wa1[j * 2 * H + H + i];
                }
                hz = fmaxf(hz, 0.f); ha = fmaxf(ha, 0.f);
                zacc += hz * Wi2[j];
                for (int e = 0; e < E; ++e) aacc[e] += ha * Wa2[e * H + j];
            }
            #pragma unroll
            for (int off = 4; off >= 1; off >>= 1) {
                zacc += __shfl_down(zacc, off, 8);
                for (int e = 0; e < E; ++e) aacc[e] += __shfl_down(aacc[e], off, 8);
            }
            if (js == 0) {
                zl[ml] = zacc + bi2[0];
                for (int e = 0; e < E; ++e) al[ml][e] = aacc[e] + ba2[e];
            }
        }
        __syncthreads();
        if (t < M) {
            const int m = t;
            float v[3] = { zl[m * L + 0], zl[m * L + 1], zl[m * L + 2] };
            int di = 0; float dv = v[0];
            for (int i = 1; i < 3; ++i) if (v[i] <= dv) { dv = v[i]; di = i; }
            float mx = -1e30f;
            for (int i = 0; i < 3; ++i) if (i != di) mx = fmaxf(mx, v[i]);
            float s = 0.f, ev[3];
            for (int i = 0; i < 3; ++i) { ev[i] = (i == di) ? 0.f : expf(v[i] - mx); s += ev[i]; }
            for (int i = 0; i < 3; ++i) zeta_all[m][i] = ev[i] / s;
            for (int l = 0; l < L; ++l) {
                float a[4];
                for (int e = 0; e < 4; ++e) a[e] = al[m * L + l][e];
                int i1 = 0;
                for (int e = 1; e < 4; ++e) if (a[e] > a[i1]) i1 = e;
                int i2 = -1;
                for (int e = 0; e < 4; ++e) { if (e == i1) continue; if (i2 < 0 || a[e] > a[i2]) i2 = e; }
                const float mx2 = fmaxf(a[i1], a[i2]);
                const float e1 = expf(a[i1] - mx2), e2 = expf(a[i2] - mx2);
                const float ss = e1 + e2;
                for (int e = 0; e < 4; ++e) alpha_all[m][l][e] = 0.f;
                alpha_all[m][l][i1] = e1 / ss;
                alpha_all[m][l][i2] = e2 / ss;
            }
        }
        __syncthreads();
        if (t < M) {
            const int m = t;
            float Rrow[8]; float rs = 0.f;
            for (int n = 0; n < M; ++n) {
                const float g = gate_logits[m * M + n];
                const float rr = log1pf(expf(g)) * R_benefit[m * M + n];
                Rrow[n] = rr; rs += rr;
            }
            rs = fmaxf(rs, 1e-12f);
            for (int l = 0; l < L; ++l) {
                float zag = 0.f, aag[4] = {0.f, 0.f, 0.f, 0.f};
                for (int n = 0; n < M; ++n) {
                    const float w = Rrow[n] / rs;
                    zag += w * zeta_all[n][l];
                    for (int e = 0; e < 4; ++e) aag[e] += w * alpha_all[n][l][e];
                }
                for (int e = 0; e < 4; ++e) salpha[(m * L + l) * 4 + e] = zag * aag[e];
            }
        }
    } else if (blk <= 6816) {
        // ---- cvt: f32 -> bf16, W1|W2|W3|A1|A2|A3 contiguous ----
        const int i = (blk - 1) * 256 + t;   // float4 index, exact fit (6816*256 = b5)
        constexpr int b0 = 1048576;
        constexpr int b1 = b0 + 524288;
        constexpr int b2 = b1 + 131072;
        constexpr int b3 = b2 + 16384;
        constexpr int b4 = b3 + 16384;
        const float* src; int rel;
        if (i < b0)      { src = s0; rel = i; }
        else if (i < b1) { src = s1; rel = i - b0; }
        else if (i < b2) { src = s2; rel = i - b1; }
        else if (i < b3) { src = s3; rel = i - b2; }
        else if (i < b4) { src = s4; rel = i - b3; }
        else             { src = s5; rel = i - b4; }
        const float4 v = ((const float4*)src)[rel];
        bf16x4_v o;
        o[0] = (__bf16)v.x; o[1] = (__bf16)v.y; o[2] = (__bf16)v.z; o[3] = (__bf16)v.w;
        ((bf16x4_v*)wdst)[i] = o;
    } else {
        // ---- bepi pack: B [E][Dout][r] f32 -> [Dout][32] bf16, c=e*8+r ----
        const int idx = (blk - 6817) * 256 + t;   // exact fit (448*256 = c3)
        constexpr int c1 = 2048 * 32, c2 = c1 + 1024 * 32;
        const float* B; int rel, Dout;
        if (idx < c1)      { B = B1; rel = idx;      Dout = 2048; }
        else if (idx < c2) { B = B2; rel = idx - c1; Dout = 1024; }
        else               { B = B3; rel = idx - c2; Dout = 512; }
        const int o = rel >> 5, c = rel & 31, e = c >> 3, r = c & 7;
        bedst[idx] = (__bf16)B[((size_t)e * Dout + o) * 8 + r];
    }
}

// ---------------- TW[b][c] = (sum_k h[b][k]*Acat[c][k]) * salpha[dom[b]][layer][c>>3]
template<bool F32IN>
__global__ void __launch_bounds__(256) tw_kernel(
    const void* __restrict__ hin, bf16_t* __restrict__ xb_out,
    const bf16_t* __restrict__ Acat, const float* __restrict__ salpha,
    const int* __restrict__ dom, const int layer, const int K,
    bf16_t* __restrict__ TWb)
{
    const int t = threadIdx.x, wid = t >> 6, lane = t & 63;
    const int rb = blockIdx.x * 64 + wid * 16;
    const int ln15 = lane & 15, kg = (lane >> 4) * 8;
    const int row = rb + ln15;
    const int Kh = K >> 1;
    f32x4 a0l = {0.f,0.f,0.f,0.f}, a1l = {0.f,0.f,0.f,0.f};
    f32x4 a0h = {0.f,0.f,0.f,0.f}, a1h = {0.f,0.f,0.f,0.f};
    const bf16_t* pa0 = Acat + (size_t)ln15 * K + kg;
    const bf16_t* pa1 = pa0 + (size_t)16 * K;
    for (int k0 = 0; k0 < Kh; k0 += 32) {
        bf16x8 al, ah;
        if constexpr (F32IN) {
            const float* px = (const float*)hin + (size_t)row * K + k0 + kg;
            const float4 x0 = *(const float4*)px;
            const float4 x1 = *(const float4*)(px + 4);
            const float4 y0 = *(const float4*)(px + Kh);
            const float4 y1 = *(const float4*)(px + Kh + 4);
            al[0] = (__bf16)x0.x; al[1] = (__bf16)x0.y; al[2] = (__bf16)x0.z; al[3] = (__bf16)x0.w;
            al[4] = (__bf16)x1.x; al[5] = (__bf16)x1.y; al[6] = (__bf16)x1.z; al[7] = (__bf16)x1.w;
            ah[0] = (__bf16)y0.x; ah[1] = (__bf16)y0.y; ah[2] = (__bf16)y0.z; ah[3] = (__bf16)y0.w;
            ah[4] = (__bf16)y1.x; ah[5] = (__bf16)y1.y; ah[6] = (__bf16)y1.z; ah[7] = (__bf16)y1.w;
            *(bf16x8*)(xb_out + (size_t)row * K + k0 + kg) = al;
            *(bf16x8*)(xb_out + (size_t)row * K + Kh + k0 + kg) = ah;
        } else {
            al = *(const bf16x8*)((const bf16_t*)hin + (size_t)row * K + k0 + kg);
            ah = *(const bf16x8*)((const bf16_t*)hin + (size_t)row * K + Kh + k0 + kg);
        }
        const bf16x8 b0l = *(const bf16x8*)(pa0 + k0);
        const bf16x8 b1l = *(const bf16x8*)(pa1 + k0);
        const bf16x8 b0h = *(const bf16x8*)(pa0 + Kh + k0);
        const bf16x8 b1h = *(const bf16x8*)(pa1 + Kh + k0);
        a0l = __builtin_amdgcn_mfma_f32_16x16x32_bf16(al, b0l, a0l, 0, 0, 0);
        a1l = __builtin_amdgcn_mfma_f32_16x16x32_bf16(al, b1l, a1l, 0, 0, 0);
        a0h = __builtin_amdgcn_mfma_f32_16x16x32_bf16(ah, b0h, a0h, 0, 0, 0);
        a1h = __builtin_amdgcn_mfma_f32_16x16x32_bf16(ah, b1h, a1h, 0, 0, 0);
    }
    const f32x4 acc0 = a0l + a0h;
    const f32x4 acc1 = a1l + a1h;
    const int rbase = rb + (lane >> 4) * 4;
    #pragma unroll
    for (int i = 0; i < 4; ++i) {
        const int r2 = rbase + i;
        const int d = dom[r2];
        const float* sa = salpha + (d * 3 + layer) * 4;
        const float s0 = sa[ln15 >> 3];
        const float s1 = sa[2 + (ln15 >> 3)];
        TWb[(size_t)r2 * 32 + ln15]      = (__bf16)(acc0[i] * s0);
        TWb[(size_t)r2 * 32 + 16 + ln15] = (__bf16)(acc1[i] * s1);
    }
}

// ================= 256x256 8-phase GEMM + fused LoRA K-step =================
// Core unchanged from R12 (1 barrier/phase, plane staging, vmcnt(4) at P2/P4,
// template<int K> 2-tile unroll; SQ_LDS_BANK_CONFLICT=0).
// R13 epilogue: per-wave LDS bounce (R8 mapping — exonerated: R8/R9's failure
// was the layer-2 template-K bug, identical absmax with/without bounce) with
// explicit compiler fences at the write->read boundary (same-wave DS ops are
// HW-in-order; only IR reordering was a hazard). Stores become full 128B
// lines (was 2B scalar stores -> WRITE_SIZE 118MB vs 67MB ideal).

__device__ __forceinline__ void stage_chunk32(const bf16_t* g, char* chunk, int t) {
    const int row = t >> 2;
    const int sl = t & 3;
    const int src = sl ^ (((row >> 3) & 1) << 1);
    gload_lds16(g + (size_t)row * 32 + src * 8, chunk + t * 16);
}

template<int K>
__global__ void __launch_bounds__(512, 2) gemm_lora8(
    const bf16_t* __restrict__ Abuf, const bf16_t* __restrict__ Wbuf,
    const float* __restrict__ bias, const bf16_t* __restrict__ TWb,
    const bf16_t* __restrict__ Bepi, bf16_t* __restrict__ outp,
    const int N, const int nwg_n)
{
    __shared__ __align__(1024) char lds[131072];
    const int t = threadIdx.x;
    const int wid = t >> 6, lane = t & 63;
    const int wm = wid >> 2, wn = wid & 3, wnh = wn >> 1;
    const int cpx = gridDim.x >> 3;
    const int wg = (blockIdx.x & 7) * cpx + (blockIdx.x >> 3);
    const int row0 = (wg / nwg_n) * 256, col0 = (wg % nwg_n) * 256;

    const int r15 = lane & 15;
    const int swb = ((lane >> 4) ^ (((lane >> 3) & 1) << 1)) << 4;

    const char* aBase = lds + (wm << 14) + (r15 << 6) + swb;
    const char* bBase = lds + 65536 + (wnh << 14) + ((wn & 1) << 12) + (r15 << 6) + swb;
    char* const dBase = lds + t * 16;

    const int srow = t >> 2, ssl = t & 3;
    const int ssrc = ssl ^ (((srow >> 3) & 1) << 1);
    const bf16_t* sA = Abuf + (size_t)(row0 + srow) * K + ssrc * 8;
    const bf16_t* sB = Wbuf + (size_t)(col0 + srow) * K + ssrc * 8;
    constexpr size_t halfA = (size_t)128 * K;

    f32x4 acc[8][4] = {};
    bf16x8 aF[4], bF[4];

    #define RD_A(P, KQ, MB) do { _Pragma("unroll") for (int i_ = 0; i_ < 4; ++i_) \
        aF[i_] = *(const bf16x8*)(aBase + (P)*32768 + (KQ)*8192 + ((MB)+i_)*1024); } while (0)
    #define RD_B(P, KQ) do { _Pragma("unroll") for (int n_ = 0; n_ < 4; ++n_) \
        bF[n_] = *(const bf16x8*)(bBase + (P)*32768 + (KQ)*8192 + n_*1024); } while (0)

    auto mfma16 = [&](int mbase) {
        __builtin_amdgcn_s_setprio(1);
        #pragma unroll
        for (int mf = 0; mf < 4; ++mf)
            #pragma unroll
            for (int nf = 0; nf < 4; ++nf)
                acc[mbase + mf][nf] =
                    __builtin_amdgcn_mfma_f32_16x16x32_bf16(aF[mf], bF[nf], acc[mbase + mf][nf], 0, 0, 0);
        __builtin_amdgcn_s_setprio(0);
    };
    #define BAR() __builtin_amdgcn_s_barrier()

    constexpr int NT = K >> 6;

    gload_lds16(sA,              dBase + 0);
    gload_lds16(sA + halfA,      dBase + 16384);
    gload_lds16(sB,              dBase + 65536);
    gload_lds16(sB + halfA,      dBase + 65536 + 16384);
    gload_lds16(sA + 32,         dBase + 8192);
    gload_lds16(sA + halfA + 32, dBase + 24576);
    gload_lds16(sB + 32,         dBase + 65536 + 8192);
    gload_lds16(sB + halfA + 32, dBase + 65536 + 24576);
    asm volatile("s_waitcnt vmcnt(4)" ::: "memory");
    __builtin_amdgcn_s_barrier();

    const bf16_t* pA0 = sA + 64;
    const bf16_t* pA1 = sA + halfA + 64;
    const bf16_t* pB0 = sB + 64;
    const bf16_t* pB1 = sB + halfA + 64;

    #define TILE(P, MORE, TOFF) do {                                            \
        RD_A(P, 0, 0);                                                           \
        RD_B(P, 0);                                                              \
        if (MORE) { gload_lds16(pA0 + (TOFF), dBase + ((P)^1)*32768 + 0);        \
                    gload_lds16(pA1 + (TOFF), dBase + ((P)^1)*32768 + 16384); }  \
        BAR();                                                                   \
        mfma16(0);                                                               \
        RD_A(P, 0, 4);                                                           \
        if (MORE) {                                                              \
            gload_lds16(pB0 + (TOFF), dBase + 65536 + ((P)^1)*32768 + 0);        \
            gload_lds16(pB1 + (TOFF), dBase + 65536 + ((P)^1)*32768 + 16384);    \
            asm volatile("s_waitcnt vmcnt(4)" ::: "memory");                     \
        } else {                                                                 \
            asm volatile("s_waitcnt vmcnt(0)" ::: "memory");                     \
        }                                                                        \
        BAR();                                                                   \
        mfma16(4);                                                               \
        RD_A(P, 1, 4);                                                           \
        RD_B(P, 1);                                                              \
        if (MORE) { gload_lds16(pA0 + (TOFF) + 32, dBase + ((P)^1)*32768 + 8192);  \
                    gload_lds16(pA1 + (TOFF) + 32, dBase + ((P)^1)*32768 + 24576);} \
        BAR();                                                                   \
        mfma16(4);                                                               \
        RD_A(P, 1, 0);                                                           \
        if (MORE) {                                                              \
            gload_lds16(pB0 + (TOFF) + 32, dBase + 65536 + ((P)^1)*32768 + 8192);  \
            gload_lds16(pB1 + (TOFF) + 32, dBase + 65536 + ((P)^1)*32768 + 24576); \
            asm volatile("s_waitcnt vmcnt(4)" ::: "memory");                     \
        }                                                                        \
        BAR();                                                                   \
        mfma16(0);                                                               \
    } while (0)

    #pragma unroll 1
    for (int T = 0; T < NT - 2; T += 2) {
        TILE(0, true, 0);
        TILE(1, true, 64);
        pA0 += 128; pA1 += 128; pB0 += 128; pB1 += 128;
    }
    TILE(0, true, 0);
    TILE(1, false, 64);

    // LoRA tail (parity-0 chunks)
    {
        __builtin_amdgcn_s_barrier();
        stage_chunk32(TWb + (size_t)row0 * 32,          lds + 0,             t);
        stage_chunk32(TWb + (size_t)(row0 + 128) * 32,  lds + 16384,         t);
        stage_chunk32(Bepi + (size_t)col0 * 32,         lds + 65536,         t);
        stage_chunk32(Bepi + (size_t)(col0 + 128) * 32, lds + 65536 + 16384, t);
        asm volatile("s_waitcnt vmcnt(0)" ::: "memory");
        __builtin_amdgcn_s_barrier();
        RD_B(0, 0);
        RD_A(0, 0, 0);
        mfma16(0);
        RD_A(0, 0, 4);
        mfma16(4);
    }

    // Epilogue: per-wave LDS bounce -> full-128B-line stores.
    // LoRA reads are consumed (lgkm-drained) before each wave's MFMAs, which
    // precede this barrier -> safe to overwrite LDS after it.
    __builtin_amdgcn_s_barrier();
    {
        char* eb = lds + wid * 2048;              // private [16 rows][128B] tile
        const int rloc = (lane >> 4) * 4;
        const int g = lane >> 4;                  // == row>>2 for this lane's rows
        const int orow0 = row0 + wm * 128;
        const int ocol0 = col0 + wn * 64;
        float bcol[4];
        #pragma unroll
        for (int nf = 0; nf < 4; ++nf) bcol[nf] = bias[ocol0 + nf * 16 + r15];
        const int rdrow = lane >> 3;              // 0..7
        const int rdcolb = (lane & 7) * 16;
        const int rdoff0 = rdrow * 128 + (rdcolb ^ ((rdrow >> 2) << 5));
        const int rdoff1 = (rdrow + 8) * 128 + (rdcolb ^ (((rdrow + 8) >> 2) << 5));
        bf16_t* outbase = outp + (size_t)ocol0 + (lane & 7) * 8;
        #pragma unroll
        for (int mf = 0; mf < 8; ++mf) {
            #pragma unroll
            for (int i = 0; i < 4; ++i) {
                const int r = rloc + i;
                #pragma unroll
                for (int nf = 0; nf < 4; ++nf) {
                    const float v = fmaxf(acc[mf][nf][i] + bcol[nf], 0.f);
                    // write block (nf^g), bank-disjoint across the 4 lane-groups
                    *(bf16_t*)(eb + r * 128 + ((nf ^ g) * 32 + r15 * 2)) = (__bf16)v;
                }
            }
            __builtin_amdgcn_sched_barrier(0);
            asm volatile("" ::: "memory");
            const bf16x8 v0 = *(const bf16x8*)(eb + rdoff0);
            const bf16x8 v1 = *(const bf16x8*)(eb + rdoff1);
            asm volatile("" ::: "memory");
            __builtin_amdgcn_sched_barrier(0);
            *(bf16x8*)(outbase + (size_t)(orow0 + mf * 16 + rdrow) * N) = v0;
            *(bf16x8*)(outbase + (size_t)(orow0 + mf * 16 + 8 + rdrow) * N) = v1;
        }
    }
    #undef TILE
    #undef RD_A
    #undef RD_B
    #undef BAR
}

// ---------------- old 128x128 GEMM (layer 3: N=512), compile-time K
#define BM 128
#define BN 128
#define BK 32

template<bool OUT_F32, int K>
__global__ void __launch_bounds__(256) gemm_lora(
    const bf16_t* __restrict__ Abuf, const bf16_t* __restrict__ Wbuf,
    const float* __restrict__ bias, const bf16_t* __restrict__ TWb,
    const bf16_t* __restrict__ Bepi, void* __restrict__ outp,
    const int N)
{
    __shared__ bf16_t lA[BM * BK];
    __shared__ bf16_t lB[BN * BK];
    const int t = threadIdx.x;
    const int row0 = blockIdx.y * BM;
    const int col0 = blockIdx.x * BN;
    const int wid = t >> 6, lane = t & 63;
    const int wr = wid >> 1, wc = wid & 1;
    const int ln15 = lane & 15, kg = (lane >> 4) * 8;
    const int srow = t >> 2, sg8 = (t & 3) * 8;
    const bf16_t* gA = Abuf + (size_t)(row0 + srow) * K + sg8;
    const bf16_t* gB = Wbuf + (size_t)(col0 + srow) * K + sg8;
    bf16_t* ldA  = &lA[t * 8];
    bf16_t* ldA2 = &lA[2048 + t * 8];
    bf16_t* ldB  = &lB[t * 8];
    bf16_t* ldB2 = &lB[2048 + t * 8];
    f32x4 acc[4][4] = {};
    const int aoff = (wr * 64 + ln15) * BK + kg;
    const int boff = (wc * 64 + ln15) * BK + kg;

    auto compute_tile = [&]() {
        bf16x8 af[4], bfr[4];
        #pragma unroll
        for (int m = 0; m < 4; ++m) af[m] = *(const bf16x8*)&lA[aoff + m * 16 * BK];
        #pragma unroll
        for (int n = 0; n < 4; ++n) bfr[n] = *(const bf16x8*)&lB[boff + n * 16 * BK];
        #pragma unroll
        for (int m = 0; m < 4; ++m)
            #pragma unroll
            for (int n = 0; n < 4; ++n)
                acc[m][n] = __builtin_amdgcn_mfma_f32_16x16x32_bf16(af[m], bfr[n], acc[m][n], 0, 0, 0);
    };

    constexpr size_t half = (size_t)64 * K;
    constexpr int nk = K / BK;
    #pragma unroll 1
    for (int kt = 0; kt < nk; ++kt) {
        gload_lds16(gA + kt * BK, ldA);
        gload_lds16(gA + half + kt * BK, ldA2);
        gload_lds16(gB + kt * BK, ldB);
        gload_lds16(gB + half + kt * BK, ldB2);
        __syncthreads();
        compute_tile();
        __syncthreads();
    }
    gload_lds16(TWb + (size_t)(row0 + srow) * 32 + sg8, ldA);
    gload_lds16(TWb + (size_t)(row0 + 64 + srow) * 32 + sg8, ldA2);
    gload_lds16(Bepi + (size_t)(col0 + srow) * 32 + sg8, ldB);
    gload_lds16(Bepi + (size_t)(col0 + 64 + srow) * 32 + sg8, ldB2);
    __syncthreads();
    compute_tile();

    const int orow = row0 + wr * 64 + (lane >> 4) * 4;
    const int ocol = col0 + wc * 64 + ln15;
    #pragma unroll
    for (int n = 0; n < 4; ++n) {
        const int col = ocol + n * 16;
        const float bn = bias[col];
        #pragma unroll
        for (int m = 0; m < 4; ++m) {
            const int rbase = orow + m * 16;
            #pragma unroll
            for (int i = 0; i < 4; ++i) {
                const float v = fmaxf(acc[m][n][i] + bn, 0.f);
                if constexpr (OUT_F32)
                    ((float*)outp)[(size_t)(rbase + i) * N + col] = v;
                else
                    ((bf16_t*)outp)[(size_t)(rbase + i) * N + col] = (__bf16)v;
            }
        }
    }
}

extern "C" void kernel_launch(void* const* d_in, const int* in_sizes, int n_in,
                              void* d_out, int out_size, void* d_ws, size_t ws_size,
                              hipStream_t stream)
{
    const float* x    = (const float*)d_in[0];
    const int*   dom  = (const int*)d_in[1];
    const float* W1   = (const float*)d_in[2];  const float* b1  = (const float*)d_in[3];
    const float* W2   = (const float*)d_in[4];  const float* b2  = (const float*)d_in[5];
    const float* W3   = (const float*)d_in[6];  const float* b3  = (const float*)d_in[7];
    const float* A1   = (const float*)d_in[8];  const float* B1  = (const float*)d_in[9];
    const float* A2   = (const float*)d_in[10]; const float* B2  = (const float*)d_in[11];
    const float* A3   = (const float*)d_in[12]; const float* B3  = (const float*)d_in[13];
    const float* dome = (const float*)d_in[14]; const float* lpos = (const float*)d_in[15];
    const float* Wi1  = (const float*)d_in[16]; const float* bi1 = (const float*)d_in[17];
    const float* Wi2  = (const float*)d_in[18]; const float* bi2 = (const float*)d_in[19];
    const float* Wa1  = (const float*)d_in[20]; const float* ba1 = (const float*)d_in[21];
    const float* Wa2  = (const float*)d_in[22]; const float* ba2 = (const float*)d_in[23];
    const float* gate = (const float*)d_in[24]; const float* Rb  = (const float*)d_in[25];
    (void)in_sizes; (void)n_in; (void)out_size; (void)ws_size;

    constexpr int Bsz = 16384, D0 = 2048, D1 = 2048, D2 = 1024, D3 = 512;

    char* ws = (char*)d_ws;
    size_t off = 0;
    auto alloc = [&](size_t bytes) -> void* {
        void* p = ws + off;
        off = (off + bytes + 255) & ~(size_t)255;
        return p;
    };
    float*  salpha = (float*) alloc(8 * 3 * 4 * sizeof(float));
    bf16_t* W1b = (bf16_t*)alloc((size_t)D1 * D0 * 2);
    bf16_t* W2b = (bf16_t*)alloc((size_t)D2 * D1 * 2);
    bf16_t* W3b = (bf16_t*)alloc((size_t)D3 * D2 * 2);
    bf16_t* Ac1 = (bf16_t*)alloc((size_t)32 * D0 * 2);
    bf16_t* Ac2 = (bf16_t*)alloc((size_t)32 * D1 * 2);
    bf16_t* Ac3 = (bf16_t*)alloc((size_t)32 * D2 * 2);
    bf16_t* Be1 = (bf16_t*)alloc((size_t)D1 * 32 * 2);
    bf16_t* Be2 = (bf16_t*)alloc((size_t)D2 * 32 * 2);
    bf16_t* Be3 = (bf16_t*)alloc((size_t)D3 * 32 * 2);
    bf16_t* TWb = (bf16_t*)alloc((size_t)Bsz * 32 * 2);
    bf16_t* xb  = (bf16_t*)alloc((size_t)Bsz * D0 * 2);
    bf16_t* h1b = (bf16_t*)alloc((size_t)Bsz * D1 * 2);
    bf16_t* h2b = xb;  // xb dead after layer-1 GEMM

    // prep: routing (block 0) + W/A convert (6816) + Bepi pack (448)
    prep_kernel<<<7265, 256, 0, stream>>>(
        dome, lpos, Wi1, bi1, Wi2, bi2, Wa1, ba1, Wa2, ba2, gate, Rb, salpha,
        W1, W2, W3, A1, A2, A3, W1b,
        B1, B2, B3, Be1);

    // layer 1: K = D0 = 2048, N = D1 = 2048 (grid 512)
    tw_kernel<true><<<Bsz / 64, 256, 0, stream>>>(x, xb, Ac1, salpha, dom, 0, D0, TWb);
    gemm_lora8<2048><<<(Bsz / 256) * (D1 / 256), 512, 0, stream>>>(xb, W1b, b1, TWb, Be1, h1b, D1, D1 / 256);
    // layer 2: K = D1 = 2048 (reduction dim), N = D2 = 1024 (grid 256)
    tw_kernel<false><<<Bsz / 64, 256, 0, stream>>>(h1b, nullptr, Ac2, salpha, dom, 1, D1, TWb);
    gemm_lora8<2048><<<(Bsz / 256) * (D2 / 256), 512, 0, stream>>>(h1b, W2b, b2, TWb, Be2, h2b, D2, D2 / 256);
    // layer 3 (f32 out, 128^2 kernel): K = D2 = 1024
    tw_kernel<false><<<Bsz / 64, 256, 0, stream>>>(h2b, nullptr, Ac3, salpha, dom, 2, D2, TWb);
    gemm_lora<true, 1024><<<dim3(D3 / BN, Bsz / BM), 256, 0, stream>>>(h2b, W3b, b3, TWb, Be3, d_out, D3);
}

// Round 14
// 358.838 us; speedup vs baseline: 1.1310x; 1.0311x over previous
//
#include <hip/hip_runtime.h>

typedef __bf16 bf16_t;
typedef __bf16 bf16x8 __attribute__((ext_vector_type(8)));
typedef __bf16 bf16x4_v __attribute__((ext_vector_type(4)));
typedef float f32x4 __attribute__((ext_vector_type(4)));

#define AS1 __attribute__((address_space(1)))
#define AS3 __attribute__((address_space(3)))

__device__ __forceinline__ void gload_lds16(const void* g, void* l) {
    __builtin_amdgcn_global_load_lds((AS1 void*)(void*)g, (AS3 void*)l, 16, 0, 0);
}

// ================= prep kernel: routing (block 0) + W/A cvt (1..6816) +
// bepi pack (6817..7264) + x->bf16 cast (7265..23648) in ONE launch.
// R14: x cast moved here from tw1 — prep runs at full occupancy (~6 TB/s)
// while tw1 had only 1024 waves (1/SIMD) for the same 201MB of traffic.
__global__ void __launch_bounds__(256) prep_kernel(
    const float* __restrict__ dom_emb, const float* __restrict__ layer_pos,
    const float* __restrict__ Wi1, const float* __restrict__ bi1,
    const float* __restrict__ Wi2, const float* __restrict__ bi2,
    const float* __restrict__ Wa1, const float* __restrict__ ba1,
    const float* __restrict__ Wa2, const float* __restrict__ ba2,
    const float* __restrict__ gate_logits, const float* __restrict__ R_benefit,
    float* __restrict__ salpha,
    const float* __restrict__ s0, const float* __restrict__ s1,
    const float* __restrict__ s2, const float* __restrict__ s3,
    const float* __restrict__ s4, const float* __restrict__ s5,
    bf16_t* __restrict__ wdst,
    const float* __restrict__ B1, const float* __restrict__ B2,
    const float* __restrict__ B3, bf16_t* __restrict__ bedst,
    const float* __restrict__ x, bf16_t* __restrict__ xb)
{
    const int blk = blockIdx.x;
    const int t = threadIdx.x;
    if (blk == 0) {
        // ---- routing ----
        constexpr int M = 8, L = 3, E = 4, H = 64;
        __shared__ float zl[M * L];
        __shared__ float al[M * L][E];
        __shared__ float zeta_all[M][L];
        __shared__ float alpha_all[M][L][E];
        const int ml = t >> 3, js = t & 7;
        if (ml < M * L) {
            const int m = ml / L, l = ml % L;
            float zacc = 0.f;
            float aacc[E] = {0.f, 0.f, 0.f, 0.f};
            for (int jj = 0; jj < 8; ++jj) {
                const int j = js * 8 + jj;
                float hz = bi1[j], ha = ba1[j];
                for (int i = 0; i < H; ++i) {
                    const float de = dom_emb[m * H + i];
                    const float lp = layer_pos[l * H + i];
                    hz += de * Wi1[j * 2 * H + i] + lp * Wi1[j * 2 * H + H + i];
                    ha += de * Wa1[j * 2 * H + i] + lp * Wa1[j * 2 * H + H + i];
                }
                hz = fmaxf(hz, 0.f); ha = fmaxf(ha, 0.f);
                zacc += hz * Wi2[j];
                for (int e = 0; e < E; ++e) aacc[e] += ha * Wa2[e * H + j];
            }
            #pragma unroll
            for (int off = 4; off >= 1; off >>= 1) {
                zacc += __shfl_down(zacc, off, 8);
                for (int e = 0; e < E; ++e) aacc[e] += __shfl_down(aacc[e], off, 8);
            }
            if (js == 0) {
                zl[ml] = zacc + bi2[0];
                for (int e = 0; e < E; ++e) al[ml][e] = aacc[e] + ba2[e];
            }
        }
        __syncthreads();
        if (t < M) {
            const int m = t;
            float v[3] = { zl[m * L + 0], zl[m * L + 1], zl[m * L + 2] };
            int di = 0; float dv = v[0];
            for (int i = 1; i < 3; ++i) if (v[i] <= dv) { dv = v[i]; di = i; }
            float mx = -1e30f;
            for (int i = 0; i < 3; ++i) if (i != di) mx = fmaxf(mx, v[i]);
            float s = 0.f, ev[3];
            for (int i = 0; i < 3; ++i) { ev[i] = (i == di) ? 0.f : expf(v[i] - mx); s += ev[i]; }
            for (int i = 0; i < 3; ++i) zeta_all[m][i] = ev[i] / s;
            for (int l = 0; l < L; ++l) {
                float a[4];
                for (int e = 0; e < 4; ++e) a[e] = al[m * L + l][e];
                int i1 = 0;
                for (int e = 1; e < 4; ++e) if (a[e] > a[i1]) i1 = e;
                int i2 = -1;
                for (int e = 0; e < 4; ++e) { if (e == i1) continue; if (i2 < 0 || a[e] > a[i2]) i2 = e; }
                const float mx2 = fmaxf(a[i1], a[i2]);
                const float e1 = expf(a[i1] - mx2), e2 = expf(a[i2] - mx2);
                const float ss = e1 + e2;
                for (int e = 0; e < 4; ++e) alpha_all[m][l][e] = 0.f;
                alpha_all[m][l][i1] = e1 / ss;
                alpha_all[m][l][i2] = e2 / ss;
            }
        }
        __syncthreads();
        if (t < M) {
            const int m = t;
            float Rrow[8]; float rs = 0.f;
            for (int n = 0; n < M; ++n) {
                const float g = gate_logits[m * M + n];
                const float rr = log1pf(expf(g)) * R_benefit[m * M + n];
                Rrow[n] = rr; rs += rr;
            }
            rs = fmaxf(rs, 1e-12f);
            for (int l = 0; l < L; ++l) {
                float zag = 0.f, aag[4] = {0.f, 0.f, 0.f, 0.f};
                for (int n = 0; n < M; ++n) {
                    const float w = Rrow[n] / rs;
                    zag += w * zeta_all[n][l];
                    for (int e = 0; e < 4; ++e) aag[e] += w * alpha_all[n][l][e];
                }
                for (int e = 0; e < 4; ++e) salpha[(m * L + l) * 4 + e] = zag * aag[e];
            }
        }
    } else if (blk <= 6816) {
        // ---- cvt: f32 -> bf16, W1|W2|W3|A1|A2|A3 contiguous ----
        const int i = (blk - 1) * 256 + t;
        constexpr int b0 = 1048576;
        constexpr int b1 = b0 + 524288;
        constexpr int b2 = b1 + 131072;
        constexpr int b3 = b2 + 16384;
        constexpr int b4 = b3 + 16384;
        const float* src; int rel;
        if (i < b0)      { src = s0; rel = i; }
        else if (i < b1) { src = s1; rel = i - b0; }
        else if (i < b2) { src = s2; rel = i - b1; }
        else if (i < b3) { src = s3; rel = i - b2; }
        else if (i < b4) { src = s4; rel = i - b3; }
        else             { src = s5; rel = i - b4; }
        const float4 v = ((const float4*)src)[rel];
        bf16x4_v o;
        o[0] = (__bf16)v.x; o[1] = (__bf16)v.y; o[2] = (__bf16)v.z; o[3] = (__bf16)v.w;
        ((bf16x4_v*)wdst)[i] = o;
    } else if (blk <= 7264) {
        // ---- bepi pack ----
        const int idx = (blk - 6817) * 256 + t;
        constexpr int c1 = 2048 * 32, c2 = c1 + 1024 * 32;
        const float* B; int rel, Dout;
        if (idx < c1)      { B = B1; rel = idx;      Dout = 2048; }
        else if (idx < c2) { B = B2; rel = idx - c1; Dout = 1024; }
        else               { B = B3; rel = idx - c2; Dout = 512; }
        const int o = rel >> 5, c = rel & 31, e = c >> 3, r = c & 7;
        bedst[idx] = (__bf16)B[((size_t)e * Dout + o) * 8 + r];
    } else {
        // ---- x -> bf16 cast (16384 blocks; exact fit 16384*256*8 = 16384*2048) ----
        const size_t i8 = ((size_t)(blk - 7265) * 256 + t) * 8;
        const float4 v0 = *(const float4*)(x + i8);
        const float4 v1 = *(const float4*)(x + i8 + 4);
        bf16x8 o;
        o[0] = (__bf16)v0.x; o[1] = (__bf16)v0.y; o[2] = (__bf16)v0.z; o[3] = (__bf16)v0.w;
        o[4] = (__bf16)v1.x; o[5] = (__bf16)v1.y; o[6] = (__bf16)v1.z; o[7] = (__bf16)v1.w;
        *(bf16x8*)(xb + i8) = o;
    }
}

// ---------------- TW[b][c] = (sum_k h[b][k]*Acat[c][k]) * salpha[dom[b]][layer][c>>3]
// R14: 8 waves (512 thr): waves 0-3 (h=0) rows g*16, K-half 0; waves 4-7 (h=1)
// same rows, K-half 1; f32 LDS reduction; h=0 waves scale+store. Doubles
// waves/SIMD 1->2 (tw was BW/latency-bound at low occupancy; R12 ILP null).
// Inner 2-way split retained (quarters) for MLP within each wave.
__global__ void __launch_bounds__(512) tw_kernel(
    const bf16_t* __restrict__ hin,
    const bf16_t* __restrict__ Acat, const float* __restrict__ salpha,
    const int* __restrict__ dom, const int layer, const int K,
    bf16_t* __restrict__ TWb)
{
    __shared__ float red[4 * 64 * 8];   // 8 KB
    const int t = threadIdx.x, wid = t >> 6, lane = t & 63;
    const int g = wid & 3, h = wid >> 2;
    const int rb = blockIdx.x * 64 + g * 16;
    const int ln15 = lane & 15, kg = (lane >> 4) * 8;
    const int row = rb + ln15;
    const int Kh = K >> 1, Kq = K >> 2;
    const int base = h * Kh;
    f32x4 a0l = {0.f,0.f,0.f,0.f}, a1l = {0.f,0.f,0.f,0.f};
    f32x4 a0h = {0.f,0.f,0.f,0.f}, a1h = {0.f,0.f,0.f,0.f};
    const bf16_t* ph  = hin + (size_t)row * K + base + kg;
    const bf16_t* pa0 = Acat + (size_t)ln15 * K + base + kg;
    const bf16_t* pa1 = pa0 + (size_t)16 * K;
    for (int k0 = 0; k0 < Kq; k0 += 32) {
        const bf16x8 al  = *(const bf16x8*)(ph + k0);
        const bf16x8 ah  = *(const bf16x8*)(ph + Kq + k0);
        const bf16x8 b0l = *(const bf16x8*)(pa0 + k0);
        const bf16x8 b1l = *(const bf16x8*)(pa1 + k0);
        const bf16x8 b0h = *(const bf16x8*)(pa0 + Kq + k0);
        const bf16x8 b1h = *(const bf16x8*)(pa1 + Kq + k0);
        a0l = __builtin_amdgcn_mfma_f32_16x16x32_bf16(al, b0l, a0l, 0, 0, 0);
        a1l = __builtin_amdgcn_mfma_f32_16x16x32_bf16(al, b1l, a1l, 0, 0, 0);
        a0h = __builtin_amdgcn_mfma_f32_16x16x32_bf16(ah, b0h, a0h, 0, 0, 0);
        a1h = __builtin_amdgcn_mfma_f32_16x16x32_bf16(ah, b1h, a1h, 0, 0, 0);
    }
    f32x4 acc0 = a0l + a0h;
    f32x4 acc1 = a1l + a1h;
    float* slot = red + ((g * 64 + lane) << 3);
    if (h == 1) {
        *(f32x4*)slot = acc0;
        *(f32x4*)(slot + 4) = acc1;
    }
    __syncthreads();
    if (h == 0) {
        acc0 += *(const f32x4*)slot;
        acc1 += *(const f32x4*)(slot + 4);
        const int rbase = rb + (lane >> 4) * 4;
        #pragma unroll
        for (int i = 0; i < 4; ++i) {
            const int r2 = rbase + i;
            const int d = dom[r2];
            const float* sa = salpha + (d * 3 + layer) * 4;
            const float s0 = sa[ln15 >> 3];
            const float s1 = sa[2 + (ln15 >> 3)];
            TWb[(size_t)r2 * 32 + ln15]      = (__bf16)(acc0[i] * s0);
            TWb[(size_t)r2 * 32 + 16 + ln15] = (__bf16)(acc1[i] * s1);
        }
    }
}

// ================= 256x256 8-phase GEMM + fused LoRA K-step =================
// Unchanged from R13 (1 barrier/phase, plane staging, vmcnt(4) at P2/P4,
// template<int K> 2-tile unroll, fenced LDS-bounce epilogue; conflicts 0,
// MfmaUtil ~56%).

__device__ __forceinline__ void stage_chunk32(const bf16_t* g, char* chunk, int t) {
    const int row = t >> 2;
    const int sl = t & 3;
    const int src = sl ^ (((row >> 3) & 1) << 1);
    gload_lds16(g + (size_t)row * 32 + src * 8, chunk + t * 16);
}

template<int K>
__global__ void __launch_bounds__(512, 2) gemm_lora8(
    const bf16_t* __restrict__ Abuf, const bf16_t* __restrict__ Wbuf,
    const float* __restrict__ bias, const bf16_t* __restrict__ TWb,
    const bf16_t* __restrict__ Bepi, bf16_t* __restrict__ outp,
    const int N, const int nwg_n)
{
    __shared__ __align__(1024) char lds[131072];
    const int t = threadIdx.x;
    const int wid = t >> 6, lane = t & 63;
    const int wm = wid >> 2, wn = wid & 3, wnh = wn >> 1;
    const int cpx = gridDim.x >> 3;
    const int wg = (blockIdx.x & 7) * cpx + (blockIdx.x >> 3);
    const int row0 = (wg / nwg_n) * 256, col0 = (wg % nwg_n) * 256;

    const int r15 = lane & 15;
    const int swb = ((lane >> 4) ^ (((lane >> 3) & 1) << 1)) << 4;

    const char* aBase = lds + (wm << 14) + (r15 << 6) + swb;
    const char* bBase = lds + 65536 + (wnh << 14) + ((wn & 1) << 12) + (r15 << 6) + swb;
    char* const dBase = lds + t * 16;

    const int srow = t >> 2, ssl = t & 3;
    const int ssrc = ssl ^ (((srow >> 3) & 1) << 1);
    const bf16_t* sA = Abuf + (size_t)(row0 + srow) * K + ssrc * 8;
    const bf16_t* sB = Wbuf + (size_t)(col0 + srow) * K + ssrc * 8;
    constexpr size_t halfA = (size_t)128 * K;

    f32x4 acc[8][4] = {};
    bf16x8 aF[4], bF[4];

    #define RD_A(P, KQ, MB) do { _Pragma("unroll") for (int i_ = 0; i_ < 4; ++i_) \
        aF[i_] = *(const bf16x8*)(aBase + (P)*32768 + (KQ)*8192 + ((MB)+i_)*1024); } while (0)
    #define RD_B(P, KQ) do { _Pragma("unroll") for (int n_ = 0; n_ < 4; ++n_) \
        bF[n_] = *(const bf16x8*)(bBase + (P)*32768 + (KQ)*8192 + n_*1024); } while (0)

    auto mfma16 = [&](int mbase) {
        __builtin_amdgcn_s_setprio(1);
        #pragma unroll
        for (int mf = 0; mf < 4; ++mf)
            #pragma unroll
            for (int nf = 0; nf < 4; ++nf)
                acc[mbase + mf][nf] =
                    __builtin_amdgcn_mfma_f32_16x16x32_bf16(aF[mf], bF[nf], acc[mbase + mf][nf], 0, 0, 0);
        __builtin_amdgcn_s_setprio(0);
    };
    #define BAR() __builtin_amdgcn_s_barrier()

    constexpr int NT = K >> 6;

    gload_lds16(sA,              dBase + 0);
    gload_lds16(sA + halfA,      dBase + 16384);
    gload_lds16(sB,              dBase + 65536);
    gload_lds16(sB + halfA,      dBase + 65536 + 16384);
    gload_lds16(sA + 32,         dBase + 8192);
    gload_lds16(sA + halfA + 32, dBase + 24576);
    gload_lds16(sB + 32,         dBase + 65536 + 8192);
    gload_lds16(sB + halfA + 32, dBase + 65536 + 24576);
    asm volatile("s_waitcnt vmcnt(4)" ::: "memory");
    __builtin_amdgcn_s_barrier();

    const bf16_t* pA0 = sA + 64;
    const bf16_t* pA1 = sA + halfA + 64;
    const bf16_t* pB0 = sB + 64;
    const bf16_t* pB1 = sB + halfA + 64;

    #define TILE(P, MORE, TOFF) do {                                            \
        RD_A(P, 0, 0);                                                           \
        RD_B(P, 0);                                                              \
        if (MORE) { gload_lds16(pA0 + (TOFF), dBase + ((P)^1)*32768 + 0);        \
                    gload_lds16(pA1 + (TOFF), dBase + ((P)^1)*32768 + 16384); }  \
        BAR();                                                                   \
        mfma16(0);                                                               \
        RD_A(P, 0, 4);                                                           \
        if (MORE) {                                                              \
            gload_lds16(pB0 + (TOFF), dBase + 65536 + ((P)^1)*32768 + 0);        \
            gload_lds16(pB1 + (TOFF), dBase + 65536 + ((P)^1)*32768 + 16384);    \
            asm volatile("s_waitcnt vmcnt(4)" ::: "memory");                     \
        } else {                                                                 \
            asm volatile("s_waitcnt vmcnt(0)" ::: "memory");                     \
        }                                                                        \
        BAR();                                                                   \
        mfma16(4);                                                               \
        RD_A(P, 1, 4);                                                           \
        RD_B(P, 1);                                                              \
        if (MORE) { gload_lds16(pA0 + (TOFF) + 32, dBase + ((P)^1)*32768 + 8192);  \
                    gload_lds16(pA1 + (TOFF) + 32, dBase + ((P)^1)*32768 + 24576);} \
        BAR();                                                                   \
        mfma16(4);                                                               \
        RD_A(P, 1, 0);                                                           \
        if (MORE) {                                                              \
            gload_lds16(pB0 + (TOFF) + 32, dBase + 65536 + ((P)^1)*32768 + 8192);  \
            gload_lds16(pB1 + (TOFF) + 32, dBase + 65536 + ((P)^1)*32768 + 24576); \
            asm volatile("s_waitcnt vmcnt(4)" ::: "memory");                     \
        }                                                                        \
        BAR();                                                                   \
        mfma16(0);                                                               \
    } while (0)

    #pragma unroll 1
    for (int T = 0; T < NT - 2; T += 2) {
        TILE(0, true, 0);
        TILE(1, true, 64);
        pA0 += 128; pA1 += 128; pB0 += 128; pB1 += 128;
    }
    TILE(0, true, 0);
    TILE(1, false, 64);

    // LoRA tail (parity-0 chunks)
    {
        __builtin_amdgcn_s_barrier();
        stage_chunk32(TWb + (size_t)row0 * 32,          lds + 0,             t);
        stage_chunk32(TWb + (size_t)(row0 + 128) * 32,  lds + 16384,         t);
        stage_chunk32(Bepi + (size_t)col0 * 32,         lds + 65536,         t);
        stage_chunk32(Bepi + (size_t)(col0 + 128) * 32, lds + 65536 + 16384, t);
        asm volatile("s_waitcnt vmcnt(0)" ::: "memory");
        __builtin_amdgcn_s_barrier();
        RD_B(0, 0);
        RD_A(0, 0, 0);
        mfma16(0);
        RD_A(0, 0, 4);
        mfma16(4);
    }

    // Epilogue: per-wave LDS bounce -> full-128B-line stores (R13-verified).
    __builtin_amdgcn_s_barrier();
    {
        char* eb = lds + wid * 2048;
        const int rloc = (lane >> 4) * 4;
        const int g = lane >> 4;
        const int orow0 = row0 + wm * 128;
        const int ocol0 = col0 + wn * 64;
        float bcol[4];
        #pragma unroll
        for (int nf = 0; nf < 4; ++nf) bcol[nf] = bias[ocol0 + nf * 16 + r15];
        const int rdrow = lane >> 3;
        const int rdcolb = (lane & 7) * 16;
        const int rdoff0 = rdrow * 128 + (rdcolb ^ ((rdrow >> 2) << 5));
        const int rdoff1 = (rdrow + 8) * 128 + (rdcolb ^ (((rdrow + 8) >> 2) << 5));
        bf16_t* outbase = outp + (size_t)ocol0 + (lane & 7) * 8;
        #pragma unroll
        for (int mf = 0; mf < 8; ++mf) {
            #pragma unroll
            for (int i = 0; i < 4; ++i) {
                const int r = rloc + i;
                #pragma unroll
                for (int nf = 0; nf < 4; ++nf) {
                    const float v = fmaxf(acc[mf][nf][i] + bcol[nf], 0.f);
                    *(bf16_t*)(eb + r * 128 + ((nf ^ g) * 32 + r15 * 2)) = (__bf16)v;
                }
            }
            __builtin_amdgcn_sched_barrier(0);
            asm volatile("" ::: "memory");
            const bf16x8 v0 = *(const bf16x8*)(eb + rdoff0);
            const bf16x8 v1 = *(const bf16x8*)(eb + rdoff1);
            asm volatile("" ::: "memory");
            __builtin_amdgcn_sched_barrier(0);
            *(bf16x8*)(outbase + (size_t)(orow0 + mf * 16 + rdrow) * N) = v0;
            *(bf16x8*)(outbase + (size_t)(orow0 + mf * 16 + 8 + rdrow) * N) = v1;
        }
    }
    #undef TILE
    #undef RD_A
    #undef RD_B
    #undef BAR
}

// ---------------- old 128x128 GEMM (layer 3: N=512), compile-time K
#define BM 128
#define BN 128
#define BK 32

template<bool OUT_F32, int K>
__global__ void __launch_bounds__(256) gemm_lora(
    const bf16_t* __restrict__ Abuf, const bf16_t* __restrict__ Wbuf,
    const float* __restrict__ bias, const bf16_t* __restrict__ TWb,
    const bf16_t* __restrict__ Bepi, void* __restrict__ outp,
    const int N)
{
    __shared__ bf16_t lA[BM * BK];
    __shared__ bf16_t lB[BN * BK];
    const int t = threadIdx.x;
    const int row0 = blockIdx.y * BM;
    const int col0 = blockIdx.x * BN;
    const int wid = t >> 6, lane = t & 63;
    const int wr = wid >> 1, wc = wid & 1;
    const int ln15 = lane & 15, kg = (lane >> 4) * 8;
    const int srow = t >> 2, sg8 = (t & 3) * 8;
    const bf16_t* gA = Abuf + (size_t)(row0 + srow) * K + sg8;
    const bf16_t* gB = Wbuf + (size_t)(col0 + srow) * K + sg8;
    bf16_t* ldA  = &lA[t * 8];
    bf16_t* ldA2 = &lA[2048 + t * 8];
    bf16_t* ldB  = &lB[t * 8];
    bf16_t* ldB2 = &lB[2048 + t * 8];
    f32x4 acc[4][4] = {};
    const int aoff = (wr * 64 + ln15) * BK + kg;
    const int boff = (wc * 64 + ln15) * BK + kg;

    auto compute_tile = [&]() {
        bf16x8 af[4], bfr[4];
        #pragma unroll
        for (int m = 0; m < 4; ++m) af[m] = *(const bf16x8*)&lA[aoff + m * 16 * BK];
        #pragma unroll
        for (int n = 0; n < 4; ++n) bfr[n] = *(const bf16x8*)&lB[boff + n * 16 * BK];
        #pragma unroll
        for (int m = 0; m < 4; ++m)
            #pragma unroll
            for (int n = 0; n < 4; ++n)
                acc[m][n] = __builtin_amdgcn_mfma_f32_16x16x32_bf16(af[m], bfr[n], acc[m][n], 0, 0, 0);
    };

    constexpr size_t half = (size_t)64 * K;
    constexpr int nk = K / BK;
    #pragma unroll 1
    for (int kt = 0; kt < nk; ++kt) {
        gload_lds16(gA + kt * BK, ldA);
        gload_lds16(gA + half + kt * BK, ldA2);
        gload_lds16(gB + kt * BK, ldB);
        gload_lds16(gB + half + kt * BK, ldB2);
        __syncthreads();
        compute_tile();
        __syncthreads();
    }
    gload_lds16(TWb + (size_t)(row0 + srow) * 32 + sg8, ldA);
    gload_lds16(TWb + (size_t)(row0 + 64 + srow) * 32 + sg8, ldA2);
    gload_lds16(Bepi + (size_t)(col0 + srow) * 32 + sg8, ldB);
    gload_lds16(Bepi + (size_t)(col0 + 64 + srow) * 32 + sg8, ldB2);
    __syncthreads();
    compute_tile();

    const int orow = row0 + wr * 64 + (lane >> 4) * 4;
    const int ocol = col0 + wc * 64 + ln15;
    #pragma unroll
    for (int n = 0; n < 4; ++n) {
        const int col = ocol + n * 16;
        const float bn = bias[col];
        #pragma unroll
        for (int m = 0; m < 4; ++m) {
            const int rbase = orow + m * 16;
            #pragma unroll
            for (int i = 0; i < 4; ++i) {
                const float v = fmaxf(acc[m][n][i] + bn, 0.f);
                if constexpr (OUT_F32)
                    ((float*)outp)[(size_t)(rbase + i) * N + col] = v;
                else
                    ((bf16_t*)outp)[(size_t)(rbase + i) * N + col] = (__bf16)v;
            }
        }
    }
}

extern "C" void kernel_launch(void* const* d_in, const int* in_sizes, int n_in,
                              void* d_out, int out_size, void* d_ws, size_t ws_size,
                              hipStream_t stream)
{
    const float* x    = (const float*)d_in[0];
    const int*   dom  = (const int*)d_in[1];
    const float* W1   = (const float*)d_in[2];  const float* b1  = (const float*)d_in[3];
    const float* W2   = (const float*)d_in[4];  const float* b2  = (const float*)d_in[5];
    const float* W3   = (const float*)d_in[6];  const float* b3  = (const float*)d_in[7];
    const float* A1   = (const float*)d_in[8];  const float* B1  = (const float*)d_in[9];
    const float* A2   = (const float*)d_in[10]; const float* B2  = (const float*)d_in[11];
    const float* A3   = (const float*)d_in[12]; const float* B3  = (const float*)d_in[13];
    const float* dome = (const float*)d_in[14]; const float* lpos = (const float*)d_in[15];
    const float* Wi1  = (const float*)d_in[16]; const float* bi1 = (const float*)d_in[17];
    const float* Wi2  = (const float*)d_in[18]; const float* bi2 = (const float*)d_in[19];
    const float* Wa1  = (const float*)d_in[20]; const float* ba1 = (const float*)d_in[21];
    const float* Wa2  = (const float*)d_in[22]; const float* ba2 = (const float*)d_in[23];
    const float* gate = (const float*)d_in[24]; const float* Rb  = (const float*)d_in[25];
    (void)in_sizes; (void)n_in; (void)out_size; (void)ws_size;

    constexpr int Bsz = 16384, D0 = 2048, D1 = 2048, D2 = 1024, D3 = 512;

    char* ws = (char*)d_ws;
    size_t off = 0;
    auto alloc = [&](size_t bytes) -> void* {
        void* p = ws + off;
        off = (off + bytes + 255) & ~(size_t)255;
        return p;
    };
    float*  salpha = (float*) alloc(8 * 3 * 4 * sizeof(float));
    bf16_t* W1b = (bf16_t*)alloc((size_t)D1 * D0 * 2);
    bf16_t* W2b = (bf16_t*)alloc((size_t)D2 * D1 * 2);
    bf16_t* W3b = (bf16_t*)alloc((size_t)D3 * D2 * 2);
    bf16_t* Ac1 = (bf16_t*)alloc((size_t)32 * D0 * 2);
    bf16_t* Ac2 = (bf16_t*)alloc((size_t)32 * D1 * 2);
    bf16_t* Ac3 = (bf16_t*)alloc((size_t)32 * D2 * 2);
    bf16_t* Be1 = (bf16_t*)alloc((size_t)D1 * 32 * 2);
    bf16_t* Be2 = (bf16_t*)alloc((size_t)D2 * 32 * 2);
    bf16_t* Be3 = (bf16_t*)alloc((size_t)D3 * 32 * 2);
    bf16_t* TWb = (bf16_t*)alloc((size_t)Bsz * 32 * 2);
    bf16_t* xb  = (bf16_t*)alloc((size_t)Bsz * D0 * 2);
    bf16_t* h1b = (bf16_t*)alloc((size_t)Bsz * D1 * 2);
    bf16_t* h2b = xb;  // xb dead after layer-1 GEMM

    // prep: routing (1) + W/A cvt (6816) + Bepi (448) + x cast (16384)
    prep_kernel<<<23649, 256, 0, stream>>>(
        dome, lpos, Wi1, bi1, Wi2, bi2, Wa1, ba1, Wa2, ba2, gate, Rb, salpha,
        W1, W2, W3, A1, A2, A3, W1b,
        B1, B2, B3, Be1,
        x, xb);

    // layer 1: K = D0 = 2048, N = D1 = 2048
    tw_kernel<<<Bsz / 64, 512, 0, stream>>>(xb, Ac1, salpha, dom, 0, D0, TWb);
    gemm_lora8<2048><<<(Bsz / 256) * (D1 / 256), 512, 0, stream>>>(xb, W1b, b1, TWb, Be1, h1b, D1, D1 / 256);
    // layer 2: K = D1 = 2048, N = D2 = 1024
    tw_kernel<<<Bsz / 64, 512, 0, stream>>>(h1b, Ac2, salpha, dom, 1, D1, TWb);
    gemm_lora8<2048><<<(Bsz / 256) * (D2 / 256), 512, 0, stream>>>(h1b, W2b, b2, TWb, Be2, h2b, D2, D2 / 256);
    // layer 3: K = D2 = 1024 (f32 out, 128^2 kernel)
    tw_kernel<<<Bsz / 64, 512, 0, stream>>>(h2b, Ac3, salpha, dom, 2, D2, TWb);
    gemm_lora<true, 1024><<<dim3(D3 / BN, Bsz / BM), 256, 0, stream>>>(h2b, W3b, b3, TWb, Be3, d_out, D3);
}